// Round 15
// baseline (436.369 us; speedup 1.0000x reference)
//
#include <hip/hip_runtime.h>

#define EE 2048
#define LL 512
#define BBATCH 4
#define HH 32
#define SS 64
#define EPSF 1e-5f
static constexpr size_t NEL = (size_t)BBATCH * LL * EE;  // 4,194,304

typedef __attribute__((ext_vector_type(8))) short short8;
typedef __attribute__((ext_vector_type(4))) float f32x4;

__device__ __forceinline__ unsigned short f2bf(float f) {
  union { float f; unsigned u; } x; x.f = f;
  return (unsigned short)((x.u + 0x7fffu + ((x.u >> 16) & 1u)) >> 16);
}

__device__ __forceinline__ void gload_lds16(const unsigned short* g, unsigned short* l) {
  __builtin_amdgcn_global_load_lds((const __attribute__((address_space(1))) void*)g,
                                   (__attribute__((address_space(3))) void*)l, 16, 0, 0);
}

__device__ __forceinline__ void barrier_lgkm_only() {
  asm volatile("s_waitcnt lgkmcnt(0)" ::: "memory");
  __builtin_amdgcn_sched_barrier(0);
  __builtin_amdgcn_s_barrier();
}

// ---------------- batched fp32 -> bf16 conversion (up to 4 jobs) ----------------
struct CvArgs {
  const float* s[4];
  unsigned short* d[4];
};
__global__ void __launch_bounds__(256) f2bf_batch(CvArgs a, int n4) {
  int z = blockIdx.y;
  int idx = blockIdx.x * 256 + threadIdx.x;
  if (idx >= n4) return;
  float4 v = ((const float4*)a.s[z])[idx];
  ushort4 o;
  o.x = f2bf(v.x); o.y = f2bf(v.y); o.z = f2bf(v.z); o.w = f2bf(v.w);
  ((ushort4*)a.d[z])[idx] = o;
}

// ---------------- merged weight prep: w1T, w2cat, dw1T, dw2T ----------------
__global__ void __launch_bounds__(256) wprep_kernel(const float* __restrict__ w1,
                                                    const float* __restrict__ w2,
                                                    const float* __restrict__ d1,
                                                    const float* __restrict__ d2,
                                                    unsigned short* __restrict__ w1T,
                                                    unsigned short* __restrict__ w2cat,
                                                    unsigned short* __restrict__ dw1T,
                                                    unsigned short* __restrict__ dw2T) {
  const int N0 = 256 * 2048;
  const int N1 = 10240 * 160;
  const int N2 = 128 * 2048;
  const int N3 = 2048 * 128;
  int id = blockIdx.x * 256 + threadIdx.x;
  if (id < N0) {
    int n = id >> 11, k = id & 2047;
    float v = (n < 160) ? w1[(size_t)k * 160 + n] : 0.f;
    w1T[id] = f2bf(v);
    return;
  }
  id -= N0;
  if (id < N1) {
    int n = id / 160, kq = id - n * 160;
    int j = n >> 11, e = n & 2047;
    float v = ((kq >> 5) == j) ? w2[(size_t)kq * 2048 + e] : 0.f;
    w2cat[id] = f2bf(v);
    return;
  }
  id -= N1;
  if (id < N2) {
    int n = id >> 11, k = id & 2047;
    float v = (n < 64) ? d1[(size_t)k * 64 + n] : 0.f;
    dw1T[id] = f2bf(v);
    return;
  }
  id -= N2;
  if (id < N3) {
    int n = id >> 7, k = id & 127;
    float v = (k < 64) ? d2[(size_t)k * 2048 + n] : 0.f;
    dw2T[id] = f2bf(v);
  }
}

// ---------------- fused LN + token-shift ----------------
// SIDE 0 (attn): prev state row offset 1; writes xn f32, xxm bf16 (mA=maa_x), sx f32.
// SIDE 1 (ffn): prev state row offset 0; writes o1=xk bf16 (mA), o2=xr bf16 (mB).
template <int SIDE>
__global__ void __launch_bounds__(256) ln_shift_kernel(
    const float* __restrict__ x, const float* __restrict__ state, const int* __restrict__ ip,
    const float* __restrict__ lnw, const float* __restrict__ lnb,
    const float* __restrict__ mA, const float* __restrict__ mB,
    float* __restrict__ xn_out, unsigned short* __restrict__ o1,
    float* __restrict__ sx_out, unsigned short* __restrict__ o2) {
  __shared__ float red[8];
  int tok = blockIdx.x;
  int b = tok >> 9, t = tok & 511;
  int tid = threadIdx.x;
  int e = tid * 8;
  size_t base = (size_t)tok * EE;
  float c[8], p[8];
  *(float4*)&c[0] = *(const float4*)&x[base + e];
  *(float4*)&c[4] = *(const float4*)&x[base + e + 4];
  bool hasp = (t != 0);
  if (hasp) {
    *(float4*)&p[0] = *(const float4*)&x[base - EE + e];
    *(float4*)&p[4] = *(const float4*)&x[base - EE + e + 4];
  } else {
    const float* srow = state + ((size_t)b * (2 + SS) + (size_t)(2 + SS) * (*ip) +
                                 (SIDE == 0 ? 1 : 0)) * EE;
    *(float4*)&p[0] = *(const float4*)&srow[e];
    *(float4*)&p[4] = *(const float4*)&srow[e + 4];
  }
  float sc = 0.f, sp = 0.f;
#pragma unroll
  for (int j = 0; j < 8; ++j) { sc += c[j]; sp += p[j]; }
#pragma unroll
  for (int off = 32; off >= 1; off >>= 1) {
    sc += __shfl_xor(sc, off);
    sp += __shfl_xor(sp, off);
  }
  if ((tid & 63) == 0) { red[tid >> 6] = sc; red[4 + (tid >> 6)] = sp; }
  __syncthreads();
  float mc = (red[0] + red[1] + red[2] + red[3]) * (1.f / EE);
  float mp = (red[4] + red[5] + red[6] + red[7]) * (1.f / EE);
  __syncthreads();
  float qc = 0.f, qp = 0.f;
#pragma unroll
  for (int j = 0; j < 8; ++j) {
    float dc = c[j] - mc, dp = p[j] - mp;
    qc += dc * dc; qp += dp * dp;
  }
#pragma unroll
  for (int off = 32; off >= 1; off >>= 1) {
    qc += __shfl_xor(qc, off);
    qp += __shfl_xor(qp, off);
  }
  if ((tid & 63) == 0) { red[tid >> 6] = qc; red[4 + (tid >> 6)] = qp; }
  __syncthreads();
  float rc = rsqrtf((red[0] + red[1] + red[2] + red[3]) * (1.f / EE) + EPSF);
  float rp = rsqrtf((red[4] + red[5] + red[6] + red[7]) * (1.f / EE) + EPSF);
  float wv[8], bv[8], av[8], bv2[8];
  *(float4*)&wv[0] = *(const float4*)&lnw[e];
  *(float4*)&wv[4] = *(const float4*)&lnw[e + 4];
  *(float4*)&bv[0] = *(const float4*)&lnb[e];
  *(float4*)&bv[4] = *(const float4*)&lnb[e + 4];
  *(float4*)&av[0] = *(const float4*)&mA[e];
  *(float4*)&av[4] = *(const float4*)&mA[e + 4];
  if (SIDE == 1) {
    *(float4*)&bv2[0] = *(const float4*)&mB[e];
    *(float4*)&bv2[4] = *(const float4*)&mB[e + 4];
  }
  float cn[8], sxv[8];
#pragma unroll
  for (int j = 0; j < 8; ++j) {
    float cnj = (c[j] - mc) * rc * wv[j] + bv[j];
    float pnj = hasp ? ((p[j] - mp) * rp * wv[j] + bv[j]) : p[j];
    cn[j] = cnj;
    sxv[j] = pnj - cnj;
  }
  if constexpr (SIDE == 0) {
    *(float4*)&xn_out[base + e] = *(float4*)&cn[0];
    *(float4*)&xn_out[base + e + 4] = *(float4*)&cn[4];
    *(float4*)&sx_out[base + e] = *(float4*)&sxv[0];
    *(float4*)&sx_out[base + e + 4] = *(float4*)&sxv[4];
    ushort4 xo0, xo1;
    xo0.x = f2bf(cn[0] + sxv[0] * av[0]); xo0.y = f2bf(cn[1] + sxv[1] * av[1]);
    xo0.z = f2bf(cn[2] + sxv[2] * av[2]); xo0.w = f2bf(cn[3] + sxv[3] * av[3]);
    xo1.x = f2bf(cn[4] + sxv[4] * av[4]); xo1.y = f2bf(cn[5] + sxv[5] * av[5]);
    xo1.z = f2bf(cn[6] + sxv[6] * av[6]); xo1.w = f2bf(cn[7] + sxv[7] * av[7]);
    *(ushort4*)&o1[base + e] = xo0;
    *(ushort4*)&o1[base + e + 4] = xo1;
  } else {
    ushort4 k0, k1, r0, r1;
    k0.x = f2bf(cn[0] + sxv[0] * av[0]); k0.y = f2bf(cn[1] + sxv[1] * av[1]);
    k0.z = f2bf(cn[2] + sxv[2] * av[2]); k0.w = f2bf(cn[3] + sxv[3] * av[3]);
    k1.x = f2bf(cn[4] + sxv[4] * av[4]); k1.y = f2bf(cn[5] + sxv[5] * av[5]);
    k1.z = f2bf(cn[6] + sxv[6] * av[6]); k1.w = f2bf(cn[7] + sxv[7] * av[7]);
    r0.x = f2bf(cn[0] + sxv[0] * bv2[0]); r0.y = f2bf(cn[1] + sxv[1] * bv2[1]);
    r0.z = f2bf(cn[2] + sxv[2] * bv2[2]); r0.w = f2bf(cn[3] + sxv[3] * bv2[3]);
    r1.x = f2bf(cn[4] + sxv[4] * bv2[4]); r1.y = f2bf(cn[5] + sxv[5] * bv2[5]);
    r1.z = f2bf(cn[6] + sxv[6] * bv2[6]); r1.w = f2bf(cn[7] + sxv[7] * bv2[7]);
    *(ushort4*)&o1[base + e] = k0;
    *(ushort4*)&o1[base + e + 4] = k1;
    *(ushort4*)&o2[base + e] = r0;
    *(ushort4*)&o2[base + e + 4] = r1;
  }
}

// ---------------- GEMM: single-barrier ping-pong double-buffer ----------------
// Region t: {vmcnt(0) [tile-t loads, issued a full region ago] -> s_barrier ->
//            stage(t+1 -> other buf) -> reads(t)+MFMA(t) one region}.
// Hazard safety: reads of tile t-1 are consumed by MFMAs before barrier t (compiler
// lgkmcnt), so staging t+1 into that buffer after barrier t is safe; per-wave vmcnt(0)
// before the barrier makes all staged portions visible.
template <int ROWS, int BK, int NT>
__device__ __forceinline__ void stage_mat(const unsigned short* __restrict__ base, int ld,
                                          int k0, unsigned short* dst) {
  constexpr int GPR = BK / 8;
  constexpr int L = ROWS * GPR / NT;
  int tid = threadIdx.x;
#pragma unroll
  for (int r = 0; r < L; ++r) {
    int g = r * NT + tid;
    int row = g / GPR, p = g & (GPR - 1);
    int lg = p ^ (row & (GPR - 1));  // inverse-swizzled source granule (rule #21)
    gload_lds16(base + (size_t)row * ld + k0 + lg * 8, &dst[g * 8]);
  }
}

// NT threads, WM x WN waves; per-wave tile (BM/WM) x (BN/WN).
template <int BM, int BN, int BK, int NT, int WM, int WN>
__device__ __forceinline__ void gemm_core(const unsigned short* __restrict__ A, int lda,
                                          const unsigned short* __restrict__ W, int ldw,
                                          int K, int bm, int bn, unsigned short* AsAll,
                                          unsigned short* BsAll,
                                          f32x4 (&acc)[BM / WM / 16][BN / WN / 16],
                                          int& m0o, int& n0o) {
  constexpr int FM = BM / WM / 16, FN = BN / WN / 16, KS = BK / 32;
  constexpr int GPR = BK / 8;
  int tid = threadIdx.x;
  int wave = tid >> 6, lane = tid & 63;
  int wm = wave / WN, wn = wave % WN;
  const unsigned short* Abase = A + (size_t)bm * BM * lda;
  const unsigned short* Bbase = W + (size_t)bn * BN * ldw;
  const int T = K / BK;
  // prologue: stage tile 0 into buf0
  stage_mat<BM, BK, NT>(Abase, lda, 0, AsAll);
  stage_mat<BN, BK, NT>(Bbase, ldw, 0, BsAll);
  int q = lane >> 4;
  int rA = wm * (BM / WM) + (lane & 15);
  int rB = wn * (BN / WN) + (lane & 15);
  int xrA = rA & (GPR - 1), xrB = rB & (GPR - 1);
  for (int t = 0; t < T; ++t) {
    unsigned short* As = AsAll + (t & 1) * (BM * BK);
    unsigned short* Bs = BsAll + (t & 1) * (BN * BK);
    asm volatile("s_waitcnt vmcnt(0)" ::: "memory");  // my tile-t portion landed
    __builtin_amdgcn_sched_barrier(0);
    __builtin_amdgcn_s_barrier();                     // all portions of tile t visible
    __builtin_amdgcn_sched_barrier(0);
    if (t + 1 < T) {                                  // stage t+1 into the other buffer
      stage_mat<BM, BK, NT>(Abase, lda, (t + 1) * BK, AsAll + ((t + 1) & 1) * (BM * BK));
      stage_mat<BN, BK, NT>(Bbase, ldw, (t + 1) * BK, BsAll + ((t + 1) & 1) * (BN * BK));
    }
    // reads + MFMAs in ONE scheduling region: compiler fine-interleaves via lgkmcnt.
    short8 av[KS][FM], bv[KS][FN];
#pragma unroll
    for (int ks = 0; ks < KS; ++ks) {
#pragma unroll
      for (int f = 0; f < FM; f++) {
        int p = (ks * 4 + q) ^ xrA;
        av[ks][f] = *(const short8*)&As[(rA + f * 16) * BK + p * 8];
      }
#pragma unroll
      for (int f = 0; f < FN; f++) {
        int p = (ks * 4 + q) ^ xrB;
        bv[ks][f] = *(const short8*)&Bs[(rB + f * 16) * BK + p * 8];
      }
    }
    __builtin_amdgcn_s_setprio(1);
#pragma unroll
    for (int ks = 0; ks < KS; ++ks)
#pragma unroll
      for (int fm = 0; fm < FM; fm++)
#pragma unroll
        for (int fn = 0; fn < FN; fn++)
          acc[fm][fn] = __builtin_amdgcn_mfma_f32_16x16x32_bf16(av[ks][fm], bv[ks][fn],
                                                                acc[fm][fn], 0, 0, 0);
    __builtin_amdgcn_s_setprio(0);
  }
  m0o = bm * BM + wm * (BM / WM);
  n0o = bn * BN + wn * (BN / WN);
}

// epilogue: functor f(m, n, val) per owned element
template <int FM, int FN, typename F>
__device__ __forceinline__ void epi_loop(f32x4 (&acc)[FM][FN], int m0, int n0, F f) {
  int lane = threadIdx.x & 63;
  int rl = (lane >> 4) * 4, cl = lane & 15;
#pragma unroll
  for (int fm = 0; fm < FM; fm++)
#pragma unroll
    for (int fn = 0; fn < FN; fn++)
#pragma unroll
      for (int q = 0; q < 4; q++)
        f(m0 + fm * 16 + rl + q, n0 + fn * 16 + cl, acc[fm][fn][q]);
}

// MODE 2: f32 p1+acc. 3: f32 p1+sigmoid(p2)*acc. 5: bf16 tanh. 6: f32 exp(-exp(p1[n]+acc)). 7: x5.
template <int MODE, int BM, int BN, int BK>
__global__ void __launch_bounds__(256) gemm_bt(const unsigned short* __restrict__ A, int lda,
                                               const unsigned short* __restrict__ W, int ldw,
                                               int K, int NB, void* __restrict__ Cout, int ldc,
                                               const float* __restrict__ p1,
                                               const float* __restrict__ p2,
                                               const float* __restrict__ p3) {
  __shared__ __align__(16) unsigned short As[2 * BM * BK];
  __shared__ __align__(16) unsigned short Bs[2 * BN * BK];
  int nwg = gridDim.x, bid = blockIdx.x;
  int qd = nwg >> 3;
  int wg = (bid & 7) * qd + (bid >> 3);  // bijective XCD swizzle (nwg % 8 == 0)
  int bm = wg / NB, bn = wg - bm * NB;
  f32x4 acc[BM / 32][BN / 32] = {};
  int m0, n0;
  gemm_core<BM, BN, BK, 256, 2, 2>(A, lda, W, ldw, K, bm, bn, As, Bs, acc, m0, n0);
  epi_loop(acc, m0, n0, [&](int m, int n, float val) {
    size_t o = (size_t)m * ldc + n;
    if constexpr (MODE == 2) {
      ((float*)Cout)[o] = p1[o] + val;
    } else if constexpr (MODE == 3) {
      ((float*)Cout)[o] = p1[o] + val * (1.f / (1.f + expf(-p2[o])));
    } else if constexpr (MODE == 5) {
      ((unsigned short*)Cout)[o] = f2bf(tanhf(val));
    } else if constexpr (MODE == 6) {
      ((float*)Cout)[o] = expf(-expf(p1[n] + val));
    } else {  // MODE 7: x5 assemble
      int j = n >> 11, e = n & 2047;
      size_t oe = (size_t)m * EE + e;
      float xv = p1[oe];
      float sv = p2[oe];
      float st = p3[(size_t)j * EE + e];
      ((unsigned short*)Cout)[(size_t)j * NEL + oe] = f2bf(xv + sv * (st + val));
    }
  });
}

// ---- batched 4-GEMM (k,v,r,g projections): 256^2 tile, 8 waves, per-GEMM 2-XCD pinning ----
struct Proj4Args {
  const unsigned short* A[4];
  const unsigned short* W[4];
  float* C[4];
};
__global__ void __launch_bounds__(512, 1) gemm_proj4(Proj4Args args) {
  __shared__ __align__(16) unsigned short As[2 * 256 * 64];  // 64 KB
  __shared__ __align__(16) unsigned short Bs[2 * 256 * 64];  // 64 KB
  int bid = blockIdx.x;
  int xcd = bid & 7;
  int z = xcd >> 1;
  int tile = ((xcd & 1) << 5) + (bid >> 3);
  int bm = tile >> 3, bn = tile & 7;
  f32x4 acc[8][4] = {};
  int m0, n0;
  gemm_core<256, 256, 64, 512, 2, 4>(args.A[z], EE, args.W[z], EE, EE, bm, bn, As, Bs, acc,
                                     m0, n0);
  float* C = args.C[z];
  bool silu = (z == 3);
  epi_loop(acc, m0, n0, [&](int m, int n, float val) {
    size_t o = (size_t)m * EE + n;
    C[o] = silu ? (val / (1.f + expf(-val))) : val;
  });
}

// ---- batched 2-GEMM (rr f32 ; kk = relu^2 bf16), 128^2 tile, per-GEMM 4-XCD pinning ----
__global__ void __launch_bounds__(256) gemm_ffn2(const unsigned short* A0,
                                                 const unsigned short* A1,
                                                 const unsigned short* W0,
                                                 const unsigned short* W1, float* C0,
                                                 unsigned short* C1) {
  __shared__ __align__(16) unsigned short As[2 * 128 * 64];
  __shared__ __align__(16) unsigned short Bs[2 * 128 * 64];
  int bid = blockIdx.x;
  int xcd = bid & 7;
  int z = xcd >> 2;
  int tile = ((xcd & 3) << 6) + (bid >> 3);
  int bm = tile >> 4, bn = tile & 15;
  f32x4 acc[4][4] = {};
  int m0, n0;
  gemm_core<128, 128, 64, 256, 2, 2>(z ? A1 : A0, EE, z ? W1 : W0, EE, EE, bm, bn, As, Bs,
                                     acc, m0, n0);
  epi_loop(acc, m0, n0, [&](int m, int n, float val) {
    size_t o = (size_t)m * EE + n;
    if (z == 0) {
      C0[o] = val;
    } else {
      float rv = fmaxf(val, 0.f);
      C1[o] = f2bf(rv * rv);
    }
  });
}

// ---------------- WKV scan v6: d-split (2 blocks/head), 16-step groups, no atomics ----
#define GS 16
__global__ void __launch_bounds__(512) scan_kernel(const float* __restrict__ r,
                                                   const float* __restrict__ k,
                                                   const float* __restrict__ v,
                                                   const float* __restrict__ w,
                                                   const float* __restrict__ state,
                                                   const float* __restrict__ faaaa,
                                                   const int* __restrict__ ip,
                                                   float* __restrict__ att) {
  // per (dbuf,t) row: r[64] k[64] w[64] v[32] -> 224 floats
  __shared__ float bufAll[2][GS * 224];  // 28 KB
  __shared__ float part[GS][8][34];      // 17.4 KB (pad 34: conflict-free reduce)
  int blk = blockIdx.x;
  int bh = blk >> 1, dh = blk & 1;
  int b = bh >> 5, h = bh & 31;
  int tid = threadIdx.x, wv = tid >> 6, lane = tid & 63;
  int d32 = lane & 31;
  int k0w = wv * 8 + (lane >> 5) * 4;  // this lane's 4 k-slots
  int dfull = dh * 32 + d32;
  int ii = *ip;
  const float* sb = state + ((size_t)b * (2 + SS) + (size_t)(2 + SS) * ii + 2) * EE;
  float s_[4], u_[4];
#pragma unroll
  for (int q = 0; q < 4; ++q) {
    int kk_ = k0w + q;
    s_[q] = sb[(size_t)(2 * h + (kk_ >> 5)) * EE + (kk_ & 31) * 64 + dfull];
    u_[q] = faaaa[h * 64 + kk_];
  }
  size_t base = (size_t)b * LL * EE + (size_t)h * 64;
  // loader: 16 rows x 56 float4 = 896 items; thread handles tid and tid+512 (if <896)
  int i0 = tid;
  int row0 = i0 / 56, j0 = i0 - row0 * 56;
  const float* a0; int off0, gc0;
  if (j0 < 16) { a0 = r; off0 = j0 * 4; gc0 = j0 * 4; }
  else if (j0 < 32) { a0 = k; off0 = 64 + (j0 - 16) * 4; gc0 = (j0 - 16) * 4; }
  else if (j0 < 48) { a0 = w; off0 = 128 + (j0 - 32) * 4; gc0 = (j0 - 32) * 4; }
  else { a0 = v; off0 = 192 + (j0 - 48) * 4; gc0 = dh * 32 + (j0 - 48) * 4; }
  const float* lsrc0 = a0 + base + (size_t)row0 * EE + gc0;
  int loff0 = row0 * 224 + off0;
  bool has1 = (tid < 384);
  int i1 = tid + 512;
  int row1 = i1 / 56, j1 = i1 - row1 * 56;
  const float* a1; int off1, gc1;
  if (j1 < 16) { a1 = r; off1 = j1 * 4; gc1 = j1 * 4; }
  else if (j1 < 32) { a1 = k; off1 = 64 + (j1 - 16) * 4; gc1 = (j1 - 16) * 4; }
  else if (j1 < 48) { a1 = w; off1 = 128 + (j1 - 32) * 4; gc1 = (j1 - 32) * 4; }
  else { a1 = v; off1 = 192 + (j1 - 48) * 4; gc1 = dh * 32 + (j1 - 48) * 4; }
  const float* lsrc1 = a1 + base + (size_t)row1 * EE + gc1;
  int loff1 = row1 * 224 + off1;
  // prologue: group 0
  *(float4*)&bufAll[0][loff0] = *(const float4*)lsrc0;
  if (has1) *(float4*)&bufAll[0][loff1] = *(const float4*)lsrc1;
  barrier_lgkm_only();
  for (int g = 0; g < 32; ++g) {
    int cb = g & 1;
    float4 nv0, nv1;
    if (g < 31) {
      nv0 = *(const float4*)(lsrc0 + (size_t)(g + 1) * GS * EE);
      if (has1) nv1 = *(const float4*)(lsrc1 + (size_t)(g + 1) * GS * EE);
    }
    const float* buf = bufAll[cb];
#pragma unroll
    for (int t = 0; t < GS; ++t) {
      const float* rowp = buf + t * 224;
      float vv = rowp[192 + d32];
      float acc = 0.f;
#pragma unroll
      for (int q = 0; q < 4; ++q) {
        float rk = rowp[k0w + q];
        float kk2 = rowp[64 + k0w + q];
        float wk = rowp[128 + k0w + q];
        float a = kk2 * vv;
        acc = fmaf(rk, fmaf(u_[q], a, s_[q]), acc);
        s_[q] = fmaf(wk, s_[q], a);
      }
      acc += __shfl_xor(acc, 32);   // fold the two k-sub-slots (same d)
      if (lane < 32) part[t][wv][d32] = acc;
    }
    if (g < 31) {
      float* nb = bufAll[cb ^ 1];
      *(float4*)&nb[loff0] = nv0;
      if (has1) *(float4*)&nb[loff1] = nv1;
    }
    barrier_lgkm_only();
    {
      int tt = tid >> 5, dd = tid & 31;
      float tot = part[tt][0][dd] + part[tt][1][dd] + part[tt][2][dd] + part[tt][3][dd] +
                  part[tt][4][dd] + part[tt][5][dd] + part[tt][6][dd] + part[tt][7][dd];
      att[base + (size_t)(g * GS + tt) * EE + dh * 32 + dd] = tot;
    }
    barrier_lgkm_only();
  }
}

// ---------------- GroupNorm (per head) + gate, out bf16 ----------------
__global__ void __launch_bounds__(256) gn_gate_kernel(const float* __restrict__ att,
                                                      const float* __restrict__ g,
                                                      const float* __restrict__ gnw,
                                                      const float* __restrict__ gnb,
                                                      unsigned short* __restrict__ attg) {
  int tok = blockIdx.x, tid = threadIdx.x;
  int h = tid >> 3, j = tid & 7;
  size_t base = (size_t)tok * EE + h * 64 + j * 8;
  int e = h * 64 + j * 8;
  float4 a0 = *(const float4*)&att[base];
  float4 a1 = *(const float4*)&att[base + 4];
  float s = a0.x + a0.y + a0.z + a0.w + a1.x + a1.y + a1.z + a1.w;
  s += __shfl_xor(s, 1); s += __shfl_xor(s, 2); s += __shfl_xor(s, 4);
  float mean = s * (1.f / 64.f);
  float d, q = 0.f;
  d = a0.x - mean; q += d * d; d = a0.y - mean; q += d * d;
  d = a0.z - mean; q += d * d; d = a0.w - mean; q += d * d;
  d = a1.x - mean; q += d * d; d = a1.y - mean; q += d * d;
  d = a1.z - mean; q += d * d; d = a1.w - mean; q += d * d;
  q += __shfl_xor(q, 1); q += __shfl_xor(q, 2); q += __shfl_xor(q, 4);
  float rstd = rsqrtf(q * (1.f / 64.f) + EPSF);
  float4 w0 = *(const float4*)&gnw[e], w1 = *(const float4*)&gnw[e + 4];
  float4 b0 = *(const float4*)&gnb[e], b1 = *(const float4*)&gnb[e + 4];
  float4 g0 = *(const float4*)&g[base], g1 = *(const float4*)&g[base + 4];
  ushort4 o0, o1;
  o0.x = f2bf(((a0.x - mean) * rstd * w0.x + b0.x) * g0.x);
  o0.y = f2bf(((a0.y - mean) * rstd * w0.y + b0.y) * g0.y);
  o0.z = f2bf(((a0.z - mean) * rstd * w0.z + b0.z) * g0.z);
  o0.w = f2bf(((a0.w - mean) * rstd * w0.w + b0.w) * g0.w);
  o1.x = f2bf(((a1.x - mean) * rstd * w1.x + b1.x) * g1.x);
  o1.y = f2bf(((a1.y - mean) * rstd * w1.y + b1.y) * g1.y);
  o1.z = f2bf(((a1.z - mean) * rstd * w1.z + b1.z) * g1.z);
  o1.w = f2bf(((a1.w - mean) * rstd * w1.w + b1.w) * g1.w);
  *(ushort4*)&attg[base] = o0;
  *(ushort4*)&attg[base + 4] = o1;
}

extern "C" void kernel_launch(void* const* d_in, const int* in_sizes, int n_in,
                              void* d_out, int out_size, void* d_ws, size_t ws_size,
                              hipStream_t stream) {
  const float* x = (const float*)d_in[0];
  const float* state = (const float*)d_in[1];
  const float* ln1_w = (const float*)d_in[2];
  const float* ln1_b = (const float*)d_in[3];
  const float* ln2_w = (const float*)d_in[4];
  const float* ln2_b = (const float*)d_in[5];
  const float* maa_x = (const float*)d_in[6];
  const float* maa_w1 = (const float*)d_in[7];
  const float* maa_w2 = (const float*)d_in[8];
  const float* maa_stack = (const float*)d_in[9];
  const float* time_decay = (const float*)d_in[10];
  const float* decay_w1 = (const float*)d_in[11];
  const float* decay_w2 = (const float*)d_in[12];
  const float* faaaa = (const float*)d_in[13];
  const float* Wr = (const float*)d_in[14];
  const float* Wk = (const float*)d_in[15];
  const float* Wv = (const float*)d_in[16];
  const float* Wg = (const float*)d_in[17];
  const float* Wo = (const float*)d_in[18];
  const float* gn_w = (const float*)d_in[19];
  const float* gn_b = (const float*)d_in[20];
  const float* ffn_maa_k = (const float*)d_in[21];
  const float* ffn_maa_r = (const float*)d_in[22];
  const float* fWk = (const float*)d_in[23];
  const float* fWr = (const float*)d_in[24];
  const float* fWv = (const float*)d_in[25];
  const int* ip = (const int*)d_in[26];

  char* ws = (char*)d_ws;
  const size_t MB1 = 1024 * 1024;
  unsigned short* WB0 = (unsigned short*)ws;                       // 8 MB
  unsigned short* WB1 = (unsigned short*)(ws + 8 * MB1);           // 8 MB
  float* xn = (float*)(ws + 16 * MB1);                             // 16 MB (also WB2/WB3, att)
  unsigned short* x5b = (unsigned short*)(ws + 32 * MB1);          // 5 x 8 MB
  float* wbuf = (float*)(ws + 72 * MB1);                           // 16 MB (xxm in low 8)
  float* rbuf = (float*)(ws + 88 * MB1);                           // 16 MB
  float* kbuf = (float*)(ws + 104 * MB1);                          // 16 MB
  float* vbuf = (float*)(ws + 120 * MB1);                          // 16 MB
  float* gbuf = (float*)(ws + 136 * MB1);                          // 16 MB (sx first)
  char* smalls = ws + 152 * MB1;                                   // ~6.8 MB
  unsigned short* th = (unsigned short*)smalls;                    // 1 MB
  unsigned short* w1T = (unsigned short*)(smalls + 1 * MB1);       // 1 MB
  unsigned short* w2cat = (unsigned short*)(smalls + 2 * MB1);     // 3.28 MB
  unsigned short* dw1T = (unsigned short*)(smalls + 5376 * 1024);  // 0.5 MB
  unsigned short* dw2T = (unsigned short*)(smalls + 5888 * 1024);  // 0.5 MB
  unsigned short* dt = (unsigned short*)(smalls + 6400 * 1024);    // 0.5 MB

  unsigned short* xxm = (unsigned short*)wbuf;
  float* sx = gbuf;
  float* att = xn;
  unsigned short* WB2 = (unsigned short*)xn;  // xn dead after x5 assemble
  unsigned short* WB3 = WB2 + NEL;
  unsigned short* attg = x5b;               // slot0 (dead after Wo GEMM)
  unsigned short* xkb = x5b;                // slot0 (written after Wo GEMM consumed attg)
  unsigned short* fWvB = x5b + 1 * NEL;     // slot1 (x5_1 dead after dt GEMM)
  unsigned short* xrb = x5b + 2 * NEL;      // slot2
  unsigned short* kkb = x5b + 3 * NEL;      // slot3
  unsigned short* fWkB = x5b + 4 * NEL;     // slot4 (dead after proj4)
  float* rrraw = wbuf;

  const int thr = 256;
  const int nconv = (int)(NEL / 4);

  // 1. fused LN1 + token shift -> xn, xxm, sx
  ln_shift_kernel<0><<<BBATCH * LL, thr, 0, stream>>>(x, state, ip, ln1_w, ln1_b, maa_x,
                                                      nullptr, xn, xxm, sx, nullptr);
  // 2. merged weight preps
  wprep_kernel<<<10496, thr, 0, stream>>>(maa_w1, maa_w2, decay_w1, decay_w2, w1T, w2cat,
                                          dw1T, dw2T);
  // 3. th = tanh(xxm @ w1T)
  gemm_bt<5, 64, 64, 64><<<128, thr, 0, stream>>>(xxm, 2048, w1T, 2048, 2048, 4, th, 256,
                                                  nullptr, nullptr, nullptr);
  // 4. x5 assemble: N=10240, K=160 (BK=32, T=5)
  gemm_bt<7, 128, 128, 32><<<1280, thr, 0, stream>>>(th, 256, w2cat, 160, 160, 80, x5b, 0,
                                                     xn, sx, maa_stack);
  // 5. dt = tanh(x5_1 @ dw1T)
  gemm_bt<5, 64, 64, 64><<<64, thr, 0, stream>>>(x5b + 1 * NEL, 2048, dw1T, 2048, 2048, 2,
                                                 dt, 128, nullptr, nullptr, nullptr);
  // 6. w = exp(-exp(td + dt @ dw2T)): K=128 (T=2)
  gemm_bt<6, 128, 128, 64><<<256, thr, 0, stream>>>(dt, 128, dw2T, 128, 128, 16, wbuf, 2048,
                                                    time_decay, nullptr, nullptr);
  // 7. batched conversion A: Wk,Wv,Wr,Wg
  {
    CvArgs ca;
    ca.s[0] = Wk; ca.d[0] = WB0;
    ca.s[1] = Wv; ca.d[1] = WB1;
    ca.s[2] = Wr; ca.d[2] = WB2;
    ca.s[3] = Wg; ca.d[3] = WB3;
    f2bf_batch<<<dim3(4096, 4), thr, 0, stream>>>(ca, nconv);
  }
  // 8. batched k,v,r,g projections: 256^2 tiles, grid 256 x 512 thr, 2-XCD pinning
  {
    Proj4Args pa;
    pa.A[0] = x5b + 0 * NEL; pa.W[0] = WB0; pa.C[0] = kbuf;
    pa.A[1] = x5b + 2 * NEL; pa.W[1] = WB1; pa.C[1] = vbuf;
    pa.A[2] = x5b + 3 * NEL; pa.W[2] = WB2; pa.C[2] = rbuf;
    pa.A[3] = x5b + 4 * NEL; pa.W[3] = WB3; pa.C[3] = gbuf;
    gemm_proj4<<<256, 512, 0, stream>>>(pa);
  }
  // 9. batched conversion B: Wo->WB0, fWr->WB1, fWk->slot4, fWv->slot1
  {
    CvArgs cb;
    cb.s[0] = Wo; cb.d[0] = WB0;
    cb.s[1] = fWr; cb.d[1] = WB1;
    cb.s[2] = fWk; cb.d[2] = fWkB;
    cb.s[3] = fWv; cb.d[3] = fWvB;
    f2bf_batch<<<dim3(4096, 4), thr, 0, stream>>>(cb, nconv);
  }
  // 10. scan v6 (d-split; disjoint stores, no memset needed)
  scan_kernel<<<256, 512, 0, stream>>>(rbuf, kbuf, vbuf, wbuf, state, faaaa, ip, att);
  // 11. groupnorm + gate
  gn_gate_kernel<<<BBATCH * LL, thr, 0, stream>>>(att, gbuf, gn_w, gn_b, attg);
  // 12. out = x + attg @ Wo^T
  gemm_bt<2, 128, 64, 64><<<512, thr, 0, stream>>>(attg, 2048, WB0, 2048, 2048, 32,
                                                   (float*)d_out, 2048, x, nullptr, nullptr);
  // 13. fused LN2 + FFN shift (reads d_out, writes xkb(slot0)/xrb(slot2))
  ln_shift_kernel<1><<<BBATCH * LL, thr, 0, stream>>>((const float*)d_out, state, ip, ln2_w,
                                                      ln2_b, ffn_maa_k, ffn_maa_r, nullptr,
                                                      xkb, nullptr, xrb);
  // 14. batched rr + kk: grid 512, per-GEMM 4-XCD pinning
  gemm_ffn2<<<512, thr, 0, stream>>>(xrb, xkb, WB1, fWkB, rrraw, kkb);
  // 15. out += sigmoid(rr) * (kk @ fWv^T)
  gemm_bt<3, 128, 64, 64><<<512, thr, 0, stream>>>(kkb, 2048, fWvB, 2048, 2048, 32,
                                                   (float*)d_out, 2048, (const float*)d_out,
                                                   rrraw, nullptr);
}

// Round 16
// 412.454 us; speedup vs baseline: 1.0580x; 1.0580x over previous
//
#include <hip/hip_runtime.h>

#define EE 2048
#define LL 512
#define BBATCH 4
#define HH 32
#define SS 64
#define EPSF 1e-5f
static constexpr size_t NEL = (size_t)BBATCH * LL * EE;  // 4,194,304

typedef __attribute__((ext_vector_type(8))) short short8;
typedef __attribute__((ext_vector_type(4))) float f32x4;

__device__ __forceinline__ unsigned short f2bf(float f) {
  union { float f; unsigned u; } x; x.f = f;
  return (unsigned short)((x.u + 0x7fffu + ((x.u >> 16) & 1u)) >> 16);
}

__device__ __forceinline__ void gload_lds16(const unsigned short* g, unsigned short* l) {
  __builtin_amdgcn_global_load_lds((const __attribute__((address_space(1))) void*)g,
                                   (__attribute__((address_space(3))) void*)l, 16, 0, 0);
}

template <int N>
__device__ __forceinline__ void wait_vmcnt_n() {
  if constexpr (N == 4) asm volatile("s_waitcnt vmcnt(4)" ::: "memory");
  else if constexpr (N == 6) asm volatile("s_waitcnt vmcnt(6)" ::: "memory");
  else if constexpr (N == 8) asm volatile("s_waitcnt vmcnt(8)" ::: "memory");
  else asm volatile("s_waitcnt vmcnt(0)" ::: "memory");
}

__device__ __forceinline__ void barrier_lgkm_only() {
  asm volatile("s_waitcnt lgkmcnt(0)" ::: "memory");
  __builtin_amdgcn_sched_barrier(0);
  __builtin_amdgcn_s_barrier();
}

// ---------------- batched fp32 -> bf16 conversion (up to 4 jobs) ----------------
struct CvArgs {
  const float* s[4];
  unsigned short* d[4];
};
__global__ void __launch_bounds__(256) f2bf_batch(CvArgs a, int n4) {
  int z = blockIdx.y;
  int idx = blockIdx.x * 256 + threadIdx.x;
  if (idx >= n4) return;
  float4 v = ((const float4*)a.s[z])[idx];
  ushort4 o;
  o.x = f2bf(v.x); o.y = f2bf(v.y); o.z = f2bf(v.z); o.w = f2bf(v.w);
  ((ushort4*)a.d[z])[idx] = o;
}

// ---------------- merged weight prep: w1T, w2cat, dw1T, dw2T ----------------
__global__ void __launch_bounds__(256) wprep_kernel(const float* __restrict__ w1,
                                                    const float* __restrict__ w2,
                                                    const float* __restrict__ d1,
                                                    const float* __restrict__ d2,
                                                    unsigned short* __restrict__ w1T,
                                                    unsigned short* __restrict__ w2cat,
                                                    unsigned short* __restrict__ dw1T,
                                                    unsigned short* __restrict__ dw2T) {
  const int N0 = 256 * 2048;
  const int N1 = 10240 * 160;
  const int N2 = 128 * 2048;
  const int N3 = 2048 * 128;
  int id = blockIdx.x * 256 + threadIdx.x;
  if (id < N0) {
    int n = id >> 11, k = id & 2047;
    float v = (n < 160) ? w1[(size_t)k * 160 + n] : 0.f;
    w1T[id] = f2bf(v);
    return;
  }
  id -= N0;
  if (id < N1) {
    int n = id / 160, kq = id - n * 160;
    int j = n >> 11, e = n & 2047;
    float v = ((kq >> 5) == j) ? w2[(size_t)kq * 2048 + e] : 0.f;
    w2cat[id] = f2bf(v);
    return;
  }
  id -= N1;
  if (id < N2) {
    int n = id >> 11, k = id & 2047;
    float v = (n < 64) ? d1[(size_t)k * 64 + n] : 0.f;
    dw1T[id] = f2bf(v);
    return;
  }
  id -= N2;
  if (id < N3) {
    int n = id >> 7, k = id & 127;
    float v = (k < 64) ? d2[(size_t)k * 2048 + n] : 0.f;
    dw2T[id] = f2bf(v);
  }
}

// ---------------- fused LN + token-shift ----------------
// SIDE 0 (attn): prev state row offset 1; writes xn f32, xxm bf16 (mA=maa_x), sx f32.
// SIDE 1 (ffn): prev state row offset 0; writes o1=xk bf16 (mA), o2=xr bf16 (mB).
template <int SIDE>
__global__ void __launch_bounds__(256) ln_shift_kernel(
    const float* __restrict__ x, const float* __restrict__ state, const int* __restrict__ ip,
    const float* __restrict__ lnw, const float* __restrict__ lnb,
    const float* __restrict__ mA, const float* __restrict__ mB,
    float* __restrict__ xn_out, unsigned short* __restrict__ o1,
    float* __restrict__ sx_out, unsigned short* __restrict__ o2) {
  __shared__ float red[8];
  int tok = blockIdx.x;
  int b = tok >> 9, t = tok & 511;
  int tid = threadIdx.x;
  int e = tid * 8;
  size_t base = (size_t)tok * EE;
  float c[8], p[8];
  *(float4*)&c[0] = *(const float4*)&x[base + e];
  *(float4*)&c[4] = *(const float4*)&x[base + e + 4];
  bool hasp = (t != 0);
  if (hasp) {
    *(float4*)&p[0] = *(const float4*)&x[base - EE + e];
    *(float4*)&p[4] = *(const float4*)&x[base - EE + e + 4];
  } else {
    const float* srow = state + ((size_t)b * (2 + SS) + (size_t)(2 + SS) * (*ip) +
                                 (SIDE == 0 ? 1 : 0)) * EE;
    *(float4*)&p[0] = *(const float4*)&srow[e];
    *(float4*)&p[4] = *(const float4*)&srow[e + 4];
  }
  float sc = 0.f, sp = 0.f;
#pragma unroll
  for (int j = 0; j < 8; ++j) { sc += c[j]; sp += p[j]; }
#pragma unroll
  for (int off = 32; off >= 1; off >>= 1) {
    sc += __shfl_xor(sc, off);
    sp += __shfl_xor(sp, off);
  }
  if ((tid & 63) == 0) { red[tid >> 6] = sc; red[4 + (tid >> 6)] = sp; }
  __syncthreads();
  float mc = (red[0] + red[1] + red[2] + red[3]) * (1.f / EE);
  float mp = (red[4] + red[5] + red[6] + red[7]) * (1.f / EE);
  __syncthreads();
  float qc = 0.f, qp = 0.f;
#pragma unroll
  for (int j = 0; j < 8; ++j) {
    float dc = c[j] - mc, dp = p[j] - mp;
    qc += dc * dc; qp += dp * dp;
  }
#pragma unroll
  for (int off = 32; off >= 1; off >>= 1) {
    qc += __shfl_xor(qc, off);
    qp += __shfl_xor(qp, off);
  }
  if ((tid & 63) == 0) { red[tid >> 6] = qc; red[4 + (tid >> 6)] = qp; }
  __syncthreads();
  float rc = rsqrtf((red[0] + red[1] + red[2] + red[3]) * (1.f / EE) + EPSF);
  float rp = rsqrtf((red[4] + red[5] + red[6] + red[7]) * (1.f / EE) + EPSF);
  float wv[8], bv[8], av[8], bv2[8];
  *(float4*)&wv[0] = *(const float4*)&lnw[e];
  *(float4*)&wv[4] = *(const float4*)&lnw[e + 4];
  *(float4*)&bv[0] = *(const float4*)&lnb[e];
  *(float4*)&bv[4] = *(const float4*)&lnb[e + 4];
  *(float4*)&av[0] = *(const float4*)&mA[e];
  *(float4*)&av[4] = *(const float4*)&mA[e + 4];
  if (SIDE == 1) {
    *(float4*)&bv2[0] = *(const float4*)&mB[e];
    *(float4*)&bv2[4] = *(const float4*)&mB[e + 4];
  }
  float cn[8], sxv[8];
#pragma unroll
  for (int j = 0; j < 8; ++j) {
    float cnj = (c[j] - mc) * rc * wv[j] + bv[j];
    float pnj = hasp ? ((p[j] - mp) * rp * wv[j] + bv[j]) : p[j];
    cn[j] = cnj;
    sxv[j] = pnj - cnj;
  }
  if constexpr (SIDE == 0) {
    *(float4*)&xn_out[base + e] = *(float4*)&cn[0];
    *(float4*)&xn_out[base + e + 4] = *(float4*)&cn[4];
    *(float4*)&sx_out[base + e] = *(float4*)&sxv[0];
    *(float4*)&sx_out[base + e + 4] = *(float4*)&sxv[4];
    ushort4 xo0, xo1;
    xo0.x = f2bf(cn[0] + sxv[0] * av[0]); xo0.y = f2bf(cn[1] + sxv[1] * av[1]);
    xo0.z = f2bf(cn[2] + sxv[2] * av[2]); xo0.w = f2bf(cn[3] + sxv[3] * av[3]);
    xo1.x = f2bf(cn[4] + sxv[4] * av[4]); xo1.y = f2bf(cn[5] + sxv[5] * av[5]);
    xo1.z = f2bf(cn[6] + sxv[6] * av[6]); xo1.w = f2bf(cn[7] + sxv[7] * av[7]);
    *(ushort4*)&o1[base + e] = xo0;
    *(ushort4*)&o1[base + e + 4] = xo1;
  } else {
    ushort4 k0, k1, r0, r1;
    k0.x = f2bf(cn[0] + sxv[0] * av[0]); k0.y = f2bf(cn[1] + sxv[1] * av[1]);
    k0.z = f2bf(cn[2] + sxv[2] * av[2]); k0.w = f2bf(cn[3] + sxv[3] * av[3]);
    k1.x = f2bf(cn[4] + sxv[4] * av[4]); k1.y = f2bf(cn[5] + sxv[5] * av[5]);
    k1.z = f2bf(cn[6] + sxv[6] * av[6]); k1.w = f2bf(cn[7] + sxv[7] * av[7]);
    r0.x = f2bf(cn[0] + sxv[0] * bv2[0]); r0.y = f2bf(cn[1] + sxv[1] * bv2[1]);
    r0.z = f2bf(cn[2] + sxv[2] * bv2[2]); r0.w = f2bf(cn[3] + sxv[3] * bv2[3]);
    r1.x = f2bf(cn[4] + sxv[4] * bv2[4]); r1.y = f2bf(cn[5] + sxv[5] * bv2[5]);
    r1.z = f2bf(cn[6] + sxv[6] * bv2[6]); r1.w = f2bf(cn[7] + sxv[7] * bv2[7]);
    *(ushort4*)&o1[base + e] = k0;
    *(ushort4*)&o1[base + e + 4] = k1;
    *(ushort4*)&o2[base + e] = r0;
    *(ushort4*)&o2[base + e + 4] = r1;
  }
}

// ---------------- GEMM: 2-deep counted-vmcnt pipeline (R14 / R8 region order) ----------------
template <int ROWS, int BK, int NT>
__device__ __forceinline__ void stage_mat(const unsigned short* __restrict__ base, int ld,
                                          int k0, unsigned short* dst) {
  constexpr int GPR = BK / 8;
  constexpr int L = ROWS * GPR / NT;
  int tid = threadIdx.x;
#pragma unroll
  for (int r = 0; r < L; ++r) {
    int g = r * NT + tid;
    int row = g / GPR, p = g & (GPR - 1);
    int lg = p ^ (row & (GPR - 1));  // inverse-swizzled source granule (rule #21)
    gload_lds16(base + (size_t)row * ld + k0 + lg * 8, &dst[g * 8]);
  }
}

// NT threads, WM x WN waves; per-wave tile (BM/WM) x (BN/WN).
template <int BM, int BN, int BK, int NT, int WM, int WN>
__device__ __forceinline__ void gemm_core(const unsigned short* __restrict__ A, int lda,
                                          const unsigned short* __restrict__ W, int ldw,
                                          int K, int bm, int bn, unsigned short* AsAll,
                                          unsigned short* BsAll,
                                          f32x4 (&acc)[BM / WM / 16][BN / WN / 16],
                                          int& m0o, int& n0o) {
  constexpr int FM = BM / WM / 16, FN = BN / WN / 16, KS = BK / 32;
  constexpr int GPR = BK / 8;
  constexpr int NLD = (BM + BN) * GPR / NT;  // gload_lds per tile per thread
  int tid = threadIdx.x;
  int wave = tid >> 6, lane = tid & 63;
  int wm = wave / WN, wn = wave % WN;
  const unsigned short* Abase = A + (size_t)bm * BM * lda;
  const unsigned short* Bbase = W + (size_t)bn * BN * ldw;
  const int T = K / BK;
  // prologue: stage tiles 0 and 1
  stage_mat<BM, BK, NT>(Abase, lda, 0, AsAll);
  stage_mat<BN, BK, NT>(Bbase, ldw, 0, BsAll);
  {
    int k1 = (T > 1) ? BK : 0;
    stage_mat<BM, BK, NT>(Abase, lda, k1, AsAll + BM * BK);
    stage_mat<BN, BK, NT>(Bbase, ldw, k1, BsAll + BN * BK);
  }
  int q = lane >> 4;
  int rA = wm * (BM / WM) + (lane & 15);
  int rB = wn * (BN / WN) + (lane & 15);
  int xrA = rA & (GPR - 1), xrB = rB & (GPR - 1);
  for (int t = 0; t < T; ++t) {
    unsigned short* As = AsAll + (t & 1) * (BM * BK);
    unsigned short* Bs = BsAll + (t & 1) * (BN * BK);
    wait_vmcnt_n<NLD>();               // my tile-t loads landed; tile t+1 stays in flight
    __builtin_amdgcn_s_barrier();      // everyone's tile t is in LDS
    __builtin_amdgcn_sched_barrier(0);
    short8 av[KS][FM], bv[KS][FN];
#pragma unroll
    for (int ks = 0; ks < KS; ++ks) {
#pragma unroll
      for (int f = 0; f < FM; f++) {
        int p = (ks * 4 + q) ^ xrA;
        av[ks][f] = *(const short8*)&As[(rA + f * 16) * BK + p * 8];
      }
#pragma unroll
      for (int f = 0; f < FN; f++) {
        int p = (ks * 4 + q) ^ xrB;
        bv[ks][f] = *(const short8*)&Bs[(rB + f * 16) * BK + p * 8];
      }
    }
    asm volatile("s_waitcnt lgkmcnt(0)" ::: "memory");  // my reads complete
    __builtin_amdgcn_sched_barrier(0);
    __builtin_amdgcn_s_barrier();      // all waves done reading this buffer
    int tn = t + 2;
    if (tn >= T) tn -= T;              // stale restage keeps vmcnt count uniform
    stage_mat<BM, BK, NT>(Abase, lda, tn * BK, As);
    stage_mat<BN, BK, NT>(Bbase, ldw, tn * BK, Bs);
    __builtin_amdgcn_s_setprio(1);
#pragma unroll
    for (int ks = 0; ks < KS; ++ks)
#pragma unroll
      for (int fm = 0; fm < FM; fm++)
#pragma unroll
        for (int fn = 0; fn < FN; fn++)
          acc[fm][fn] = __builtin_amdgcn_mfma_f32_16x16x32_bf16(av[ks][fm], bv[ks][fn],
                                                                acc[fm][fn], 0, 0, 0);
    __builtin_amdgcn_s_setprio(0);
  }
  m0o = bm * BM + wm * (BM / WM);
  n0o = bn * BN + wn * (BN / WN);
}

// epilogue: functor f(m, n, val) per owned element
template <int FM, int FN, typename F>
__device__ __forceinline__ void epi_loop(f32x4 (&acc)[FM][FN], int m0, int n0, F f) {
  int lane = threadIdx.x & 63;
  int rl = (lane >> 4) * 4, cl = lane & 15;
#pragma unroll
  for (int fm = 0; fm < FM; fm++)
#pragma unroll
    for (int fn = 0; fn < FN; fn++)
#pragma unroll
      for (int q = 0; q < 4; q++)
        f(m0 + fm * 16 + rl + q, n0 + fn * 16 + cl, acc[fm][fn][q]);
}

// MODE 2: f32 p1+acc. 3: f32 p1+sigmoid(p2)*acc. 5: bf16 tanh. 6: f32 exp(-exp(p1[n]+acc)). 7: x5.
template <int MODE, int BM, int BN, int BK>
__global__ void __launch_bounds__(256) gemm_bt(const unsigned short* __restrict__ A, int lda,
                                               const unsigned short* __restrict__ W, int ldw,
                                               int K, int NB, void* __restrict__ Cout, int ldc,
                                               const float* __restrict__ p1,
                                               const float* __restrict__ p2,
                                               const float* __restrict__ p3) {
  __shared__ __align__(16) unsigned short As[2 * BM * BK];
  __shared__ __align__(16) unsigned short Bs[2 * BN * BK];
  int nwg = gridDim.x, bid = blockIdx.x;
  int qd = nwg >> 3;
  int wg = (bid & 7) * qd + (bid >> 3);  // bijective XCD swizzle (nwg % 8 == 0)
  int bm = wg / NB, bn = wg - bm * NB;
  f32x4 acc[BM / 32][BN / 32] = {};
  int m0, n0;
  gemm_core<BM, BN, BK, 256, 2, 2>(A, lda, W, ldw, K, bm, bn, As, Bs, acc, m0, n0);
  epi_loop(acc, m0, n0, [&](int m, int n, float val) {
    size_t o = (size_t)m * ldc + n;
    if constexpr (MODE == 2) {
      ((float*)Cout)[o] = p1[o] + val;
    } else if constexpr (MODE == 3) {
      ((float*)Cout)[o] = p1[o] + val * (1.f / (1.f + expf(-p2[o])));
    } else if constexpr (MODE == 5) {
      ((unsigned short*)Cout)[o] = f2bf(tanhf(val));
    } else if constexpr (MODE == 6) {
      ((float*)Cout)[o] = expf(-expf(p1[n] + val));
    } else {  // MODE 7: x5 assemble
      int j = n >> 11, e = n & 2047;
      size_t oe = (size_t)m * EE + e;
      float xv = p1[oe];
      float sv = p2[oe];
      float st = p3[(size_t)j * EE + e];
      ((unsigned short*)Cout)[(size_t)j * NEL + oe] = f2bf(xv + sv * (st + val));
    }
  });
}

// ---- batched 4-GEMM (k,v,r,g projections): 256^2 tile, 8 waves, per-GEMM 2-XCD pinning ----
struct Proj4Args {
  const unsigned short* A[4];
  const unsigned short* W[4];
  float* C[4];
};
__global__ void __launch_bounds__(512, 1) gemm_proj4(Proj4Args args) {
  __shared__ __align__(16) unsigned short As[2 * 256 * 64];  // 64 KB
  __shared__ __align__(16) unsigned short Bs[2 * 256 * 64];  // 64 KB
  int bid = blockIdx.x;
  int xcd = bid & 7;
  int z = xcd >> 1;
  int tile = ((xcd & 1) << 5) + (bid >> 3);
  int bm = tile >> 3, bn = tile & 7;
  f32x4 acc[8][4] = {};
  int m0, n0;
  gemm_core<256, 256, 64, 512, 2, 4>(args.A[z], EE, args.W[z], EE, EE, bm, bn, As, Bs, acc,
                                     m0, n0);
  float* C = args.C[z];
  bool silu = (z == 3);
  epi_loop(acc, m0, n0, [&](int m, int n, float val) {
    size_t o = (size_t)m * EE + n;
    C[o] = silu ? (val / (1.f + expf(-val))) : val;
  });
}

// ---- batched 2-GEMM (rr f32 ; kk = relu^2 bf16), 128^2 tile, per-GEMM 4-XCD pinning ----
__global__ void __launch_bounds__(256) gemm_ffn2(const unsigned short* A0,
                                                 const unsigned short* A1,
                                                 const unsigned short* W0,
                                                 const unsigned short* W1, float* C0,
                                                 unsigned short* C1) {
  __shared__ __align__(16) unsigned short As[2 * 128 * 64];
  __shared__ __align__(16) unsigned short Bs[2 * 128 * 64];
  int bid = blockIdx.x;
  int xcd = bid & 7;
  int z = xcd >> 2;
  int tile = ((xcd & 3) << 6) + (bid >> 3);
  int bm = tile >> 4, bn = tile & 15;
  f32x4 acc[4][4] = {};
  int m0, n0;
  gemm_core<128, 128, 64, 256, 2, 2>(z ? A1 : A0, EE, z ? W1 : W0, EE, EE, bm, bn, As, Bs,
                                     acc, m0, n0);
  epi_loop(acc, m0, n0, [&](int m, int n, float val) {
    size_t o = (size_t)m * EE + n;
    if (z == 0) {
      C0[o] = val;
    } else {
      float rv = fmaxf(val, 0.f);
      C1[o] = f2bf(rv * rv);
    }
  });
}

// ---------------- WKV scan v7: d-split, 16-step groups, dbuf partials, 1 barrier/group ----
#define GS 16
__global__ void __launch_bounds__(512) scan_kernel(const float* __restrict__ r,
                                                   const float* __restrict__ k,
                                                   const float* __restrict__ v,
                                                   const float* __restrict__ w,
                                                   const float* __restrict__ state,
                                                   const float* __restrict__ faaaa,
                                                   const int* __restrict__ ip,
                                                   float* __restrict__ att) {
  // per (dbuf,t) row: r[64] k[64] w[64] v[32] -> 224 floats
  __shared__ float bufAll[2][GS * 224];   // 28 KB
  __shared__ float part[2][GS][8][34];    // 34.8 KB (pad 34: conflict-free reduce)
  int blk = blockIdx.x;
  int bh = blk >> 1, dh = blk & 1;
  int b = bh >> 5, h = bh & 31;
  int tid = threadIdx.x, wv = tid >> 6, lane = tid & 63;
  int d32 = lane & 31;
  int k0w = wv * 8 + (lane >> 5) * 4;  // this lane's 4 k-slots
  int dfull = dh * 32 + d32;
  int ii = *ip;
  const float* sb = state + ((size_t)b * (2 + SS) + (size_t)(2 + SS) * ii + 2) * EE;
  float s_[4], u_[4];
#pragma unroll
  for (int q = 0; q < 4; ++q) {
    int kk_ = k0w + q;
    s_[q] = sb[(size_t)(2 * h + (kk_ >> 5)) * EE + (kk_ & 31) * 64 + dfull];
    u_[q] = faaaa[h * 64 + kk_];
  }
  size_t base = (size_t)b * LL * EE + (size_t)h * 64;
  // loader: 16 rows x 56 float4 = 896 items; thread handles tid and tid+512 (if <896)
  int i0 = tid;
  int row0 = i0 / 56, j0 = i0 - row0 * 56;
  const float* a0; int off0, gc0;
  if (j0 < 16) { a0 = r; off0 = j0 * 4; gc0 = j0 * 4; }
  else if (j0 < 32) { a0 = k; off0 = 64 + (j0 - 16) * 4; gc0 = (j0 - 16) * 4; }
  else if (j0 < 48) { a0 = w; off0 = 128 + (j0 - 32) * 4; gc0 = (j0 - 32) * 4; }
  else { a0 = v; off0 = 192 + (j0 - 48) * 4; gc0 = dh * 32 + (j0 - 48) * 4; }
  const float* lsrc0 = a0 + base + (size_t)row0 * EE + gc0;
  int loff0 = row0 * 224 + off0;
  bool has1 = (tid < 384);
  int i1 = tid + 512;
  int row1 = i1 / 56, j1 = i1 - row1 * 56;
  const float* a1; int off1, gc1;
  if (j1 < 16) { a1 = r; off1 = j1 * 4; gc1 = j1 * 4; }
  else if (j1 < 32) { a1 = k; off1 = 64 + (j1 - 16) * 4; gc1 = (j1 - 16) * 4; }
  else if (j1 < 48) { a1 = w; off1 = 128 + (j1 - 32) * 4; gc1 = (j1 - 32) * 4; }
  else { a1 = v; off1 = 192 + (j1 - 48) * 4; gc1 = dh * 32 + (j1 - 48) * 4; }
  const float* lsrc1 = a1 + base + (size_t)row1 * EE + gc1;
  int loff1 = row1 * 224 + off1;
  // prologue: group 0
  *(float4*)&bufAll[0][loff0] = *(const float4*)lsrc0;
  if (has1) *(float4*)&bufAll[0][loff1] = *(const float4*)lsrc1;
  barrier_lgkm_only();
  for (int g = 0; g < 32; ++g) {
    int cb = g & 1;
    float4 nv0, nv1;
    if (g < 31) {
      nv0 = *(const float4*)(lsrc0 + (size_t)(g + 1) * GS * EE);
      if (has1) nv1 = *(const float4*)(lsrc1 + (size_t)(g + 1) * GS * EE);
    }
    const float* buf = bufAll[cb];
#pragma unroll
    for (int t = 0; t < GS; ++t) {
      const float* rowp = buf + t * 224;
      float vv = rowp[192 + d32];
      float acc = 0.f;
#pragma unroll
      for (int q = 0; q < 4; ++q) {
        float rk = rowp[k0w + q];
        float kk2 = rowp[64 + k0w + q];
        float wk = rowp[128 + k0w + q];
        float a = kk2 * vv;
        acc = fmaf(rk, fmaf(u_[q], a, s_[q]), acc);
        s_[q] = fmaf(wk, s_[q], a);
      }
      acc += __shfl_xor(acc, 32);   // fold the two k-sub-slots (same d)
      if (lane < 32) part[cb][t][wv][d32] = acc;
    }
    if (g < 31) {
      float* nb = bufAll[cb ^ 1];
      *(float4*)&nb[loff0] = nv0;
      if (has1) *(float4*)&nb[loff1] = nv1;
    }
    barrier_lgkm_only();
    // reduce(g) reads part[cb]; next group's compute writes part[cb^1] (disjoint);
    // part[cb] is only rewritten after barrier(g+1), which follows this reduce.
    {
      int tt = tid >> 5, dd = tid & 31;
      float tot = part[cb][tt][0][dd] + part[cb][tt][1][dd] + part[cb][tt][2][dd] +
                  part[cb][tt][3][dd] + part[cb][tt][4][dd] + part[cb][tt][5][dd] +
                  part[cb][tt][6][dd] + part[cb][tt][7][dd];
      att[base + (size_t)(g * GS + tt) * EE + dh * 32 + dd] = tot;
    }
  }
}

// ---------------- GroupNorm (per head) + gate, out bf16 ----------------
__global__ void __launch_bounds__(256) gn_gate_kernel(const float* __restrict__ att,
                                                      const float* __restrict__ g,
                                                      const float* __restrict__ gnw,
                                                      const float* __restrict__ gnb,
                                                      unsigned short* __restrict__ attg) {
  int tok = blockIdx.x, tid = threadIdx.x;
  int h = tid >> 3, j = tid & 7;
  size_t base = (size_t)tok * EE + h * 64 + j * 8;
  int e = h * 64 + j * 8;
  float4 a0 = *(const float4*)&att[base];
  float4 a1 = *(const float4*)&att[base + 4];
  float s = a0.x + a0.y + a0.z + a0.w + a1.x + a1.y + a1.z + a1.w;
  s += __shfl_xor(s, 1); s += __shfl_xor(s, 2); s += __shfl_xor(s, 4);
  float mean = s * (1.f / 64.f);
  float d, q = 0.f;
  d = a0.x - mean; q += d * d; d = a0.y - mean; q += d * d;
  d = a0.z - mean; q += d * d; d = a0.w - mean; q += d * d;
  d = a1.x - mean; q += d * d; d = a1.y - mean; q += d * d;
  d = a1.z - mean; q += d * d; d = a1.w - mean; q += d * d;
  q += __shfl_xor(q, 1); q += __shfl_xor(q, 2); q += __shfl_xor(q, 4);
  float rstd = rsqrtf(q * (1.f / 64.f) + EPSF);
  float4 w0 = *(const float4*)&gnw[e], w1 = *(const float4*)&gnw[e + 4];
  float4 b0 = *(const float4*)&gnb[e], b1 = *(const float4*)&gnb[e + 4];
  float4 g0 = *(const float4*)&g[base], g1 = *(const float4*)&g[base + 4];
  ushort4 o0, o1;
  o0.x = f2bf(((a0.x - mean) * rstd * w0.x + b0.x) * g0.x);
  o0.y = f2bf(((a0.y - mean) * rstd * w0.y + b0.y) * g0.y);
  o0.z = f2bf(((a0.z - mean) * rstd * w0.z + b0.z) * g0.z);
  o0.w = f2bf(((a0.w - mean) * rstd * w0.w + b0.w) * g0.w);
  o1.x = f2bf(((a1.x - mean) * rstd * w1.x + b1.x) * g1.x);
  o1.y = f2bf(((a1.y - mean) * rstd * w1.y + b1.y) * g1.y);
  o1.z = f2bf(((a1.z - mean) * rstd * w1.z + b1.z) * g1.z);
  o1.w = f2bf(((a1.w - mean) * rstd * w1.w + b1.w) * g1.w);
  *(ushort4*)&attg[base] = o0;
  *(ushort4*)&attg[base + 4] = o1;
}

extern "C" void kernel_launch(void* const* d_in, const int* in_sizes, int n_in,
                              void* d_out, int out_size, void* d_ws, size_t ws_size,
                              hipStream_t stream) {
  const float* x = (const float*)d_in[0];
  const float* state = (const float*)d_in[1];
  const float* ln1_w = (const float*)d_in[2];
  const float* ln1_b = (const float*)d_in[3];
  const float* ln2_w = (const float*)d_in[4];
  const float* ln2_b = (const float*)d_in[5];
  const float* maa_x = (const float*)d_in[6];
  const float* maa_w1 = (const float*)d_in[7];
  const float* maa_w2 = (const float*)d_in[8];
  const float* maa_stack = (const float*)d_in[9];
  const float* time_decay = (const float*)d_in[10];
  const float* decay_w1 = (const float*)d_in[11];
  const float* decay_w2 = (const float*)d_in[12];
  const float* faaaa = (const float*)d_in[13];
  const float* Wr = (const float*)d_in[14];
  const float* Wk = (const float*)d_in[15];
  const float* Wv = (const float*)d_in[16];
  const float* Wg = (const float*)d_in[17];
  const float* Wo = (const float*)d_in[18];
  const float* gn_w = (const float*)d_in[19];
  const float* gn_b = (const float*)d_in[20];
  const float* ffn_maa_k = (const float*)d_in[21];
  const float* ffn_maa_r = (const float*)d_in[22];
  const float* fWk = (const float*)d_in[23];
  const float* fWr = (const float*)d_in[24];
  const float* fWv = (const float*)d_in[25];
  const int* ip = (const int*)d_in[26];

  char* ws = (char*)d_ws;
  const size_t MB1 = 1024 * 1024;
  unsigned short* WB0 = (unsigned short*)ws;                       // 8 MB
  unsigned short* WB1 = (unsigned short*)(ws + 8 * MB1);           // 8 MB
  float* xn = (float*)(ws + 16 * MB1);                             // 16 MB (also WB2/WB3, att)
  unsigned short* x5b = (unsigned short*)(ws + 32 * MB1);          // 5 x 8 MB
  float* wbuf = (float*)(ws + 72 * MB1);                           // 16 MB (xxm in low 8)
  float* rbuf = (float*)(ws + 88 * MB1);                           // 16 MB
  float* kbuf = (float*)(ws + 104 * MB1);                          // 16 MB
  float* vbuf = (float*)(ws + 120 * MB1);                          // 16 MB
  float* gbuf = (float*)(ws + 136 * MB1);                          // 16 MB (sx first)
  char* smalls = ws + 152 * MB1;                                   // ~6.8 MB
  unsigned short* th = (unsigned short*)smalls;                    // 1 MB
  unsigned short* w1T = (unsigned short*)(smalls + 1 * MB1);       // 1 MB
  unsigned short* w2cat = (unsigned short*)(smalls + 2 * MB1);     // 3.28 MB
  unsigned short* dw1T = (unsigned short*)(smalls + 5376 * 1024);  // 0.5 MB
  unsigned short* dw2T = (unsigned short*)(smalls + 5888 * 1024);  // 0.5 MB
  unsigned short* dt = (unsigned short*)(smalls + 6400 * 1024);    // 0.5 MB

  unsigned short* xxm = (unsigned short*)wbuf;
  float* sx = gbuf;
  float* att = xn;
  unsigned short* WB2 = (unsigned short*)xn;  // xn dead after x5 assemble
  unsigned short* WB3 = WB2 + NEL;
  unsigned short* attg = x5b;               // slot0 (dead after Wo GEMM)
  unsigned short* xkb = x5b;                // slot0 (written after Wo GEMM consumed attg)
  unsigned short* fWvB = x5b + 1 * NEL;     // slot1 (x5_1 dead after dt GEMM)
  unsigned short* xrb = x5b + 2 * NEL;      // slot2
  unsigned short* kkb = x5b + 3 * NEL;      // slot3
  unsigned short* fWkB = x5b + 4 * NEL;     // slot4 (dead after proj4)
  float* rrraw = wbuf;

  const int thr = 256;
  const int nconv = (int)(NEL / 4);

  // 1. fused LN1 + token shift -> xn, xxm, sx
  ln_shift_kernel<0><<<BBATCH * LL, thr, 0, stream>>>(x, state, ip, ln1_w, ln1_b, maa_x,
                                                      nullptr, xn, xxm, sx, nullptr);
  // 2. merged weight preps
  wprep_kernel<<<10496, thr, 0, stream>>>(maa_w1, maa_w2, decay_w1, decay_w2, w1T, w2cat,
                                          dw1T, dw2T);
  // 3. th = tanh(xxm @ w1T)
  gemm_bt<5, 64, 64, 64><<<128, thr, 0, stream>>>(xxm, 2048, w1T, 2048, 2048, 4, th, 256,
                                                  nullptr, nullptr, nullptr);
  // 4. x5 assemble: N=10240, K=160 (BK=32, T=5)
  gemm_bt<7, 128, 128, 32><<<1280, thr, 0, stream>>>(th, 256, w2cat, 160, 160, 80, x5b, 0,
                                                     xn, sx, maa_stack);
  // 5. dt = tanh(x5_1 @ dw1T)
  gemm_bt<5, 64, 64, 64><<<64, thr, 0, stream>>>(x5b + 1 * NEL, 2048, dw1T, 2048, 2048, 2,
                                                 dt, 128, nullptr, nullptr, nullptr);
  // 6. w = exp(-exp(td + dt @ dw2T)): K=128 (T=2)
  gemm_bt<6, 128, 128, 64><<<256, thr, 0, stream>>>(dt, 128, dw2T, 128, 128, 16, wbuf, 2048,
                                                    time_decay, nullptr, nullptr);
  // 7. batched conversion A: Wk,Wv,Wr,Wg
  {
    CvArgs ca;
    ca.s[0] = Wk; ca.d[0] = WB0;
    ca.s[1] = Wv; ca.d[1] = WB1;
    ca.s[2] = Wr; ca.d[2] = WB2;
    ca.s[3] = Wg; ca.d[3] = WB3;
    f2bf_batch<<<dim3(4096, 4), thr, 0, stream>>>(ca, nconv);
  }
  // 8. batched k,v,r,g projections: 256^2 tiles, grid 256 x 512 thr, 2-XCD pinning
  {
    Proj4Args pa;
    pa.A[0] = x5b + 0 * NEL; pa.W[0] = WB0; pa.C[0] = kbuf;
    pa.A[1] = x5b + 2 * NEL; pa.W[1] = WB1; pa.C[1] = vbuf;
    pa.A[2] = x5b + 3 * NEL; pa.W[2] = WB2; pa.C[2] = rbuf;
    pa.A[3] = x5b + 4 * NEL; pa.W[3] = WB3; pa.C[3] = gbuf;
    gemm_proj4<<<256, 512, 0, stream>>>(pa);
  }
  // 9. batched conversion B: Wo->WB0, fWr->WB1, fWk->slot4, fWv->slot1
  {
    CvArgs cb;
    cb.s[0] = Wo; cb.d[0] = WB0;
    cb.s[1] = fWr; cb.d[1] = WB1;
    cb.s[2] = fWk; cb.d[2] = fWkB;
    cb.s[3] = fWv; cb.d[3] = fWvB;
    f2bf_batch<<<dim3(4096, 4), thr, 0, stream>>>(cb, nconv);
  }
  // 10. scan v7 (d-split; disjoint stores; dbuf partials, 1 barrier/group)
  scan_kernel<<<256, 512, 0, stream>>>(rbuf, kbuf, vbuf, wbuf, state, faaaa, ip, att);
  // 11. groupnorm + gate
  gn_gate_kernel<<<BBATCH * LL, thr, 0, stream>>>(att, gbuf, gn_w, gn_b, attg);
  // 12. out = x + attg @ Wo^T
  gemm_bt<2, 128, 64, 64><<<512, thr, 0, stream>>>(attg, 2048, WB0, 2048, 2048, 32,
                                                   (float*)d_out, 2048, x, nullptr, nullptr);
  // 13. fused LN2 + FFN shift (reads d_out, writes xkb(slot0)/xrb(slot2))
  ln_shift_kernel<1><<<BBATCH * LL, thr, 0, stream>>>((const float*)d_out, state, ip, ln2_w,
                                                      ln2_b, ffn_maa_k, ffn_maa_r, nullptr,
                                                      xkb, nullptr, xrb);
  // 14. batched rr + kk: grid 512, per-GEMM 4-XCD pinning
  gemm_ffn2<<<512, thr, 0, stream>>>(xrb, xkb, WB1, fWkB, rrraw, kkb);
  // 15. out += sigmoid(rr) * (kk @ fWv^T)
  gemm_bt<3, 128, 64, 64><<<512, thr, 0, stream>>>(kkb, 2048, fWvB, 2048, 2048, 32,
                                                   (float*)d_out, 2048, (const float*)d_out,
                                                   rrraw, nullptr);
}

// Round 17
// 409.991 us; speedup vs baseline: 1.0643x; 1.0060x over previous
//
#include <hip/hip_runtime.h>

#define EE 2048
#define LL 512
#define BBATCH 4
#define HH 32
#define SS 64
#define EPSF 1e-5f
static constexpr size_t NEL = (size_t)BBATCH * LL * EE;  // 4,194,304

typedef __attribute__((ext_vector_type(8))) short short8;
typedef __attribute__((ext_vector_type(4))) float f32x4;

__device__ __forceinline__ unsigned short f2bf(float f) {
  union { float f; unsigned u; } x; x.f = f;
  return (unsigned short)((x.u + 0x7fffu + ((x.u >> 16) & 1u)) >> 16);
}

__device__ __forceinline__ void gload_lds16(const unsigned short* g, unsigned short* l) {
  __builtin_amdgcn_global_load_lds((const __attribute__((address_space(1))) void*)g,
                                   (__attribute__((address_space(3))) void*)l, 16, 0, 0);
}

template <int N>
__device__ __forceinline__ void wait_vmcnt_n() {
  if constexpr (N == 4) asm volatile("s_waitcnt vmcnt(4)" ::: "memory");
  else if constexpr (N == 6) asm volatile("s_waitcnt vmcnt(6)" ::: "memory");
  else if constexpr (N == 8) asm volatile("s_waitcnt vmcnt(8)" ::: "memory");
  else asm volatile("s_waitcnt vmcnt(0)" ::: "memory");
}

__device__ __forceinline__ void barrier_lgkm_only() {
  asm volatile("s_waitcnt lgkmcnt(0)" ::: "memory");
  __builtin_amdgcn_sched_barrier(0);
  __builtin_amdgcn_s_barrier();
}

// ---------------- batched fp32 -> bf16 conversion (up to 4 jobs) ----------------
struct CvArgs {
  const float* s[4];
  unsigned short* d[4];
};
__global__ void __launch_bounds__(256) f2bf_batch(CvArgs a, int n4) {
  int z = blockIdx.y;
  int idx = blockIdx.x * 256 + threadIdx.x;
  if (idx >= n4) return;
  float4 v = ((const float4*)a.s[z])[idx];
  ushort4 o;
  o.x = f2bf(v.x); o.y = f2bf(v.y); o.z = f2bf(v.z); o.w = f2bf(v.w);
  ((ushort4*)a.d[z])[idx] = o;
}

// ---------------- merged weight prep: w1T, w2cat, dw1T, dw2T ----------------
__global__ void __launch_bounds__(256) wprep_kernel(const float* __restrict__ w1,
                                                    const float* __restrict__ w2,
                                                    const float* __restrict__ d1,
                                                    const float* __restrict__ d2,
                                                    unsigned short* __restrict__ w1T,
                                                    unsigned short* __restrict__ w2cat,
                                                    unsigned short* __restrict__ dw1T,
                                                    unsigned short* __restrict__ dw2T) {
  const int N0 = 256 * 2048;
  const int N1 = 10240 * 160;
  const int N2 = 128 * 2048;
  const int N3 = 2048 * 128;
  int id = blockIdx.x * 256 + threadIdx.x;
  if (id < N0) {
    int n = id >> 11, k = id & 2047;
    float v = (n < 160) ? w1[(size_t)k * 160 + n] : 0.f;
    w1T[id] = f2bf(v);
    return;
  }
  id -= N0;
  if (id < N1) {
    int n = id / 160, kq = id - n * 160;
    int j = n >> 11, e = n & 2047;
    float v = ((kq >> 5) == j) ? w2[(size_t)kq * 2048 + e] : 0.f;
    w2cat[id] = f2bf(v);
    return;
  }
  id -= N1;
  if (id < N2) {
    int n = id >> 11, k = id & 2047;
    float v = (n < 64) ? d1[(size_t)k * 64 + n] : 0.f;
    dw1T[id] = f2bf(v);
    return;
  }
  id -= N2;
  if (id < N3) {
    int n = id >> 7, k = id & 127;
    float v = (k < 64) ? d2[(size_t)k * 2048 + n] : 0.f;
    dw2T[id] = f2bf(v);
  }
}

// ---------------- fused LN + token-shift ----------------
template <int SIDE>
__global__ void __launch_bounds__(256) ln_shift_kernel(
    const float* __restrict__ x, const float* __restrict__ state, const int* __restrict__ ip,
    const float* __restrict__ lnw, const float* __restrict__ lnb,
    const float* __restrict__ mA, const float* __restrict__ mB,
    float* __restrict__ xn_out, unsigned short* __restrict__ o1,
    float* __restrict__ sx_out, unsigned short* __restrict__ o2) {
  __shared__ float red[8];
  int tok = blockIdx.x;
  int b = tok >> 9, t = tok & 511;
  int tid = threadIdx.x;
  int e = tid * 8;
  size_t base = (size_t)tok * EE;
  float c[8], p[8];
  *(float4*)&c[0] = *(const float4*)&x[base + e];
  *(float4*)&c[4] = *(const float4*)&x[base + e + 4];
  bool hasp = (t != 0);
  if (hasp) {
    *(float4*)&p[0] = *(const float4*)&x[base - EE + e];
    *(float4*)&p[4] = *(const float4*)&x[base - EE + e + 4];
  } else {
    const float* srow = state + ((size_t)b * (2 + SS) + (size_t)(2 + SS) * (*ip) +
                                 (SIDE == 0 ? 1 : 0)) * EE;
    *(float4*)&p[0] = *(const float4*)&srow[e];
    *(float4*)&p[4] = *(const float4*)&srow[e + 4];
  }
  float sc = 0.f, sp = 0.f;
#pragma unroll
  for (int j = 0; j < 8; ++j) { sc += c[j]; sp += p[j]; }
#pragma unroll
  for (int off = 32; off >= 1; off >>= 1) {
    sc += __shfl_xor(sc, off);
    sp += __shfl_xor(sp, off);
  }
  if ((tid & 63) == 0) { red[tid >> 6] = sc; red[4 + (tid >> 6)] = sp; }
  __syncthreads();
  float mc = (red[0] + red[1] + red[2] + red[3]) * (1.f / EE);
  float mp = (red[4] + red[5] + red[6] + red[7]) * (1.f / EE);
  __syncthreads();
  float qc = 0.f, qp = 0.f;
#pragma unroll
  for (int j = 0; j < 8; ++j) {
    float dc = c[j] - mc, dp = p[j] - mp;
    qc += dc * dc; qp += dp * dp;
  }
#pragma unroll
  for (int off = 32; off >= 1; off >>= 1) {
    qc += __shfl_xor(qc, off);
    qp += __shfl_xor(qp, off);
  }
  if ((tid & 63) == 0) { red[tid >> 6] = qc; red[4 + (tid >> 6)] = qp; }
  __syncthreads();
  float rc = rsqrtf((red[0] + red[1] + red[2] + red[3]) * (1.f / EE) + EPSF);
  float rp = rsqrtf((red[4] + red[5] + red[6] + red[7]) * (1.f / EE) + EPSF);
  float wv[8], bv[8], av[8], bv2[8];
  *(float4*)&wv[0] = *(const float4*)&lnw[e];
  *(float4*)&wv[4] = *(const float4*)&lnw[e + 4];
  *(float4*)&bv[0] = *(const float4*)&lnb[e];
  *(float4*)&bv[4] = *(const float4*)&lnb[e + 4];
  *(float4*)&av[0] = *(const float4*)&mA[e];
  *(float4*)&av[4] = *(const float4*)&mA[e + 4];
  if (SIDE == 1) {
    *(float4*)&bv2[0] = *(const float4*)&mB[e];
    *(float4*)&bv2[4] = *(const float4*)&mB[e + 4];
  }
  float cn[8], sxv[8];
#pragma unroll
  for (int j = 0; j < 8; ++j) {
    float cnj = (c[j] - mc) * rc * wv[j] + bv[j];
    float pnj = hasp ? ((p[j] - mp) * rp * wv[j] + bv[j]) : p[j];
    cn[j] = cnj;
    sxv[j] = pnj - cnj;
  }
  if constexpr (SIDE == 0) {
    *(float4*)&xn_out[base + e] = *(float4*)&cn[0];
    *(float4*)&xn_out[base + e + 4] = *(float4*)&cn[4];
    *(float4*)&sx_out[base + e] = *(float4*)&sxv[0];
    *(float4*)&sx_out[base + e + 4] = *(float4*)&sxv[4];
    ushort4 xo0, xo1;
    xo0.x = f2bf(cn[0] + sxv[0] * av[0]); xo0.y = f2bf(cn[1] + sxv[1] * av[1]);
    xo0.z = f2bf(cn[2] + sxv[2] * av[2]); xo0.w = f2bf(cn[3] + sxv[3] * av[3]);
    xo1.x = f2bf(cn[4] + sxv[4] * av[4]); xo1.y = f2bf(cn[5] + sxv[5] * av[5]);
    xo1.z = f2bf(cn[6] + sxv[6] * av[6]); xo1.w = f2bf(cn[7] + sxv[7] * av[7]);
    *(ushort4*)&o1[base + e] = xo0;
    *(ushort4*)&o1[base + e + 4] = xo1;
  } else {
    ushort4 k0, k1, r0, r1;
    k0.x = f2bf(cn[0] + sxv[0] * av[0]); k0.y = f2bf(cn[1] + sxv[1] * av[1]);
    k0.z = f2bf(cn[2] + sxv[2] * av[2]); k0.w = f2bf(cn[3] + sxv[3] * av[3]);
    k1.x = f2bf(cn[4] + sxv[4] * av[4]); k1.y = f2bf(cn[5] + sxv[5] * av[5]);
    k1.z = f2bf(cn[6] + sxv[6] * av[6]); k1.w = f2bf(cn[7] + sxv[7] * av[7]);
    r0.x = f2bf(cn[0] + sxv[0] * bv2[0]); r0.y = f2bf(cn[1] + sxv[1] * bv2[1]);
    r0.z = f2bf(cn[2] + sxv[2] * bv2[2]); r0.w = f2bf(cn[3] + sxv[3] * bv2[3]);
    r1.x = f2bf(cn[4] + sxv[4] * bv2[4]); r1.y = f2bf(cn[5] + sxv[5] * bv2[5]);
    r1.z = f2bf(cn[6] + sxv[6] * bv2[6]); r1.w = f2bf(cn[7] + sxv[7] * bv2[7]);
    *(ushort4*)&o1[base + e] = k0;
    *(ushort4*)&o1[base + e + 4] = k1;
    *(ushort4*)&o2[base + e] = r0;
    *(ushort4*)&o2[base + e + 4] = r1;
  }
}

// ---------------- GEMM: 2-deep counted-vmcnt pipeline ----------------
template <int ROWS, int BK, int NT>
__device__ __forceinline__ void stage_mat(const unsigned short* __restrict__ base, int ld,
                                          int k0, unsigned short* dst) {
  constexpr int GPR = BK / 8;
  constexpr int L = ROWS * GPR / NT;
  int tid = threadIdx.x;
#pragma unroll
  for (int r = 0; r < L; ++r) {
    int g = r * NT + tid;
    int row = g / GPR, p = g & (GPR - 1);
    int lg = p ^ (row & (GPR - 1));  // inverse-swizzled source granule (rule #21)
    gload_lds16(base + (size_t)row * ld + k0 + lg * 8, &dst[g * 8]);
  }
}

// NT threads, WM x WN waves; per-wave tile (BM/WM) x (BN/WN).
// SPLIT (KS>=2 only): region A = all ds_reads + MFMA(ks=0) interleaved (reads covered);
// then drain/barrier/restage; region B = MFMA(ks>=1) covers restage.
template <int BM, int BN, int BK, int NT, int WM, int WN, bool SPLIT = false>
__device__ __forceinline__ void gemm_core(const unsigned short* __restrict__ A, int lda,
                                          const unsigned short* __restrict__ W, int ldw,
                                          int K, int bm, int bn, unsigned short* AsAll,
                                          unsigned short* BsAll,
                                          f32x4 (&acc)[BM / WM / 16][BN / WN / 16],
                                          int& m0o, int& n0o) {
  constexpr int FM = BM / WM / 16, FN = BN / WN / 16, KS = BK / 32;
  constexpr int GPR = BK / 8;
  constexpr int NLD = (BM + BN) * GPR / NT;  // gload_lds per tile per thread
  int tid = threadIdx.x;
  int wave = tid >> 6, lane = tid & 63;
  int wm = wave / WN, wn = wave % WN;
  const unsigned short* Abase = A + (size_t)bm * BM * lda;
  const unsigned short* Bbase = W + (size_t)bn * BN * ldw;
  const int T = K / BK;
  // prologue: stage tiles 0 and 1
  stage_mat<BM, BK, NT>(Abase, lda, 0, AsAll);
  stage_mat<BN, BK, NT>(Bbase, ldw, 0, BsAll);
  {
    int k1 = (T > 1) ? BK : 0;
    stage_mat<BM, BK, NT>(Abase, lda, k1, AsAll + BM * BK);
    stage_mat<BN, BK, NT>(Bbase, ldw, k1, BsAll + BN * BK);
  }
  int q = lane >> 4;
  int rA = wm * (BM / WM) + (lane & 15);
  int rB = wn * (BN / WN) + (lane & 15);
  int xrA = rA & (GPR - 1), xrB = rB & (GPR - 1);
  for (int t = 0; t < T; ++t) {
    unsigned short* As = AsAll + (t & 1) * (BM * BK);
    unsigned short* Bs = BsAll + (t & 1) * (BN * BK);
    wait_vmcnt_n<NLD>();               // my tile-t loads landed; tile t+1 stays in flight
    __builtin_amdgcn_s_barrier();      // everyone's tile t is in LDS
    __builtin_amdgcn_sched_barrier(0);
    short8 av[KS][FM], bv[KS][FN];
#pragma unroll
    for (int ks = 0; ks < KS; ++ks) {
#pragma unroll
      for (int f = 0; f < FM; f++) {
        int p = (ks * 4 + q) ^ xrA;
        av[ks][f] = *(const short8*)&As[(rA + f * 16) * BK + p * 8];
      }
#pragma unroll
      for (int f = 0; f < FN; f++) {
        int p = (ks * 4 + q) ^ xrB;
        bv[ks][f] = *(const short8*)&Bs[(rB + f * 16) * BK + p * 8];
      }
    }
    if constexpr (SPLIT && KS >= 2) {
      // region A: MFMA(ks=0) in same region as reads -> compiler interleaves
#pragma unroll
      for (int fm = 0; fm < FM; fm++)
#pragma unroll
        for (int fn = 0; fn < FN; fn++)
          acc[fm][fn] = __builtin_amdgcn_mfma_f32_16x16x32_bf16(av[0][fm], bv[0][fn],
                                                                acc[fm][fn], 0, 0, 0);
    }
    asm volatile("s_waitcnt lgkmcnt(0)" ::: "memory");  // all reads of this buffer done
    __builtin_amdgcn_sched_barrier(0);
    __builtin_amdgcn_s_barrier();      // all waves done reading this buffer
    int tn = t + 2;
    if (tn >= T) tn -= T;              // stale restage keeps vmcnt count uniform
    stage_mat<BM, BK, NT>(Abase, lda, tn * BK, As);
    stage_mat<BN, BK, NT>(Bbase, ldw, tn * BK, Bs);
    __builtin_amdgcn_s_setprio(1);
    if constexpr (SPLIT && KS >= 2) {
#pragma unroll
      for (int ks = 1; ks < KS; ++ks)
#pragma unroll
        for (int fm = 0; fm < FM; fm++)
#pragma unroll
          for (int fn = 0; fn < FN; fn++)
            acc[fm][fn] = __builtin_amdgcn_mfma_f32_16x16x32_bf16(av[ks][fm], bv[ks][fn],
                                                                  acc[fm][fn], 0, 0, 0);
    } else {
#pragma unroll
      for (int ks = 0; ks < KS; ++ks)
#pragma unroll
        for (int fm = 0; fm < FM; fm++)
#pragma unroll
          for (int fn = 0; fn < FN; fn++)
            acc[fm][fn] = __builtin_amdgcn_mfma_f32_16x16x32_bf16(av[ks][fm], bv[ks][fn],
                                                                  acc[fm][fn], 0, 0, 0);
    }
    __builtin_amdgcn_s_setprio(0);
  }
  m0o = bm * BM + wm * (BM / WM);
  n0o = bn * BN + wn * (BN / WN);
}

// epilogue: functor f(m, n, val) per owned element
template <int FM, int FN, typename F>
__device__ __forceinline__ void epi_loop(f32x4 (&acc)[FM][FN], int m0, int n0, F f) {
  int lane = threadIdx.x & 63;
  int rl = (lane >> 4) * 4, cl = lane & 15;
#pragma unroll
  for (int fm = 0; fm < FM; fm++)
#pragma unroll
    for (int fn = 0; fn < FN; fn++)
#pragma unroll
      for (int q = 0; q < 4; q++)
        f(m0 + fm * 16 + rl + q, n0 + fn * 16 + cl, acc[fm][fn][q]);
}

// MODE 2: f32 p1+acc. 3: f32 p1+sigmoid(p2)*acc. 5: bf16 tanh. 6: f32 exp(-exp(p1[n]+acc)). 7: x5.
template <int MODE, int BM, int BN, int BK>
__global__ void __launch_bounds__(256) gemm_bt(const unsigned short* __restrict__ A, int lda,
                                               const unsigned short* __restrict__ W, int ldw,
                                               int K, int NB, void* __restrict__ Cout, int ldc,
                                               const float* __restrict__ p1,
                                               const float* __restrict__ p2,
                                               const float* __restrict__ p3) {
  __shared__ __align__(16) unsigned short As[2 * BM * BK];
  __shared__ __align__(16) unsigned short Bs[2 * BN * BK];
  int nwg = gridDim.x, bid = blockIdx.x;
  int qd = nwg >> 3;
  int wg = (bid & 7) * qd + (bid >> 3);  // bijective XCD swizzle (nwg % 8 == 0)
  int bm = wg / NB, bn = wg - bm * NB;
  f32x4 acc[BM / 32][BN / 32] = {};
  int m0, n0;
  gemm_core<BM, BN, BK, 256, 2, 2>(A, lda, W, ldw, K, bm, bn, As, Bs, acc, m0, n0);
  epi_loop(acc, m0, n0, [&](int m, int n, float val) {
    size_t o = (size_t)m * ldc + n;
    if constexpr (MODE == 2) {
      ((float*)Cout)[o] = p1[o] + val;
    } else if constexpr (MODE == 3) {
      ((float*)Cout)[o] = p1[o] + val * (1.f / (1.f + expf(-p2[o])));
    } else if constexpr (MODE == 5) {
      ((unsigned short*)Cout)[o] = f2bf(tanhf(val));
    } else if constexpr (MODE == 6) {
      ((float*)Cout)[o] = expf(-expf(p1[n] + val));
    } else {  // MODE 7: x5 assemble
      int j = n >> 11, e = n & 2047;
      size_t oe = (size_t)m * EE + e;
      float xv = p1[oe];
      float sv = p2[oe];
      float st = p3[(size_t)j * EE + e];
      ((unsigned short*)Cout)[(size_t)j * NEL + oe] = f2bf(xv + sv * (st + val));
    }
  });
}

// ---- batched 4-GEMM (k,v,r,g projections): 256^2 tile, 8 waves, 2-XCD pinning, SPLIT ----
struct Proj4Args {
  const unsigned short* A[4];
  const unsigned short* W[4];
  float* C[4];
};
__global__ void __launch_bounds__(512, 1) gemm_proj4(Proj4Args args) {
  __shared__ __align__(16) unsigned short As[2 * 256 * 64];  // 64 KB
  __shared__ __align__(16) unsigned short Bs[2 * 256 * 64];  // 64 KB
  int bid = blockIdx.x;
  int xcd = bid & 7;
  int z = xcd >> 1;
  int tile = ((xcd & 1) << 5) + (bid >> 3);
  int bm = tile >> 3, bn = tile & 7;
  f32x4 acc[8][4] = {};
  int m0, n0;
  gemm_core<256, 256, 64, 512, 2, 4, true>(args.A[z], EE, args.W[z], EE, EE, bm, bn, As, Bs,
                                           acc, m0, n0);
  float* C = args.C[z];
  bool silu = (z == 3);
  epi_loop(acc, m0, n0, [&](int m, int n, float val) {
    size_t o = (size_t)m * EE + n;
    C[o] = silu ? (val / (1.f + expf(-val))) : val;
  });
}

// ---- batched 2-GEMM (rr f32 ; kk = relu^2 bf16), 128^2 tile, per-GEMM 4-XCD pinning ----
__global__ void __launch_bounds__(256) gemm_ffn2(const unsigned short* A0,
                                                 const unsigned short* A1,
                                                 const unsigned short* W0,
                                                 const unsigned short* W1, float* C0,
                                                 unsigned short* C1) {
  __shared__ __align__(16) unsigned short As[2 * 128 * 64];
  __shared__ __align__(16) unsigned short Bs[2 * 128 * 64];
  int bid = blockIdx.x;
  int xcd = bid & 7;
  int z = xcd >> 2;
  int tile = ((xcd & 3) << 6) + (bid >> 3);
  int bm = tile >> 4, bn = tile & 15;
  f32x4 acc[4][4] = {};
  int m0, n0;
  gemm_core<128, 128, 64, 256, 2, 2>(z ? A1 : A0, EE, z ? W1 : W0, EE, EE, bm, bn, As, Bs,
                                     acc, m0, n0);
  epi_loop(acc, m0, n0, [&](int m, int n, float val) {
    size_t o = (size_t)m * EE + n;
    if (z == 0) {
      C0[o] = val;
    } else {
      float rv = fmaxf(val, 0.f);
      C1[o] = f2bf(rv * rv);
    }
  });
}

// ---------------- WKV scan v8: d-split, 16-step groups, 2-deep prefetch ----------------
#define GS 16
__global__ void __launch_bounds__(512) scan_kernel(const float* __restrict__ r,
                                                   const float* __restrict__ k,
                                                   const float* __restrict__ v,
                                                   const float* __restrict__ w,
                                                   const float* __restrict__ state,
                                                   const float* __restrict__ faaaa,
                                                   const int* __restrict__ ip,
                                                   float* __restrict__ att) {
  // per (dbuf,t) row: r[64] k[64] w[64] v[32] -> 224 floats
  __shared__ float bufAll[2][GS * 224];   // 28 KB
  __shared__ float part[2][GS][8][34];    // 34.8 KB (pad 34: conflict-free reduce)
  int blk = blockIdx.x;
  int bh = blk >> 1, dh = blk & 1;
  int b = bh >> 5, h = bh & 31;
  int tid = threadIdx.x, wv = tid >> 6, lane = tid & 63;
  int d32 = lane & 31;
  int k0w = wv * 8 + (lane >> 5) * 4;  // this lane's 4 k-slots
  int dfull = dh * 32 + d32;
  int ii = *ip;
  const float* sb = state + ((size_t)b * (2 + SS) + (size_t)(2 + SS) * ii + 2) * EE;
  float s_[4], u_[4];
#pragma unroll
  for (int q = 0; q < 4; ++q) {
    int kk_ = k0w + q;
    s_[q] = sb[(size_t)(2 * h + (kk_ >> 5)) * EE + (kk_ & 31) * 64 + dfull];
    u_[q] = faaaa[h * 64 + kk_];
  }
  size_t base = (size_t)b * LL * EE + (size_t)h * 64;
  // loader: 16 rows x 56 float4 = 896 items; thread handles tid and tid+512 (if <896)
  int i0 = tid;
  int row0 = i0 / 56, j0 = i0 - row0 * 56;
  const float* a0p; int off0, gc0;
  if (j0 < 16) { a0p = r; off0 = j0 * 4; gc0 = j0 * 4; }
  else if (j0 < 32) { a0p = k; off0 = 64 + (j0 - 16) * 4; gc0 = (j0 - 16) * 4; }
  else if (j0 < 48) { a0p = w; off0 = 128 + (j0 - 32) * 4; gc0 = (j0 - 32) * 4; }
  else { a0p = v; off0 = 192 + (j0 - 48) * 4; gc0 = dh * 32 + (j0 - 48) * 4; }
  const float* lsrc0 = a0p + base + (size_t)row0 * EE + gc0;
  int loff0 = row0 * 224 + off0;
  bool has1 = (tid < 384);
  int i1 = tid + 512;
  int row1 = i1 / 56, j1 = i1 - row1 * 56;
  const float* a1p; int off1, gc1;
  if (j1 < 16) { a1p = r; off1 = j1 * 4; gc1 = j1 * 4; }
  else if (j1 < 32) { a1p = k; off1 = 64 + (j1 - 16) * 4; gc1 = (j1 - 16) * 4; }
  else if (j1 < 48) { a1p = w; off1 = 128 + (j1 - 32) * 4; gc1 = (j1 - 32) * 4; }
  else { a1p = v; off1 = 192 + (j1 - 48) * 4; gc1 = dh * 32 + (j1 - 48) * 4; }
  const float* lsrc1 = a1p + base + (size_t)row1 * EE + gc1;
  int loff1 = row1 * 224 + off1;

  auto compute = [&](const float* buf, float (*pt)[8][34]) {
#pragma unroll
    for (int t = 0; t < GS; ++t) {
      const float* rowp = buf + t * 224;
      float vv = rowp[192 + d32];
      float acc = 0.f;
#pragma unroll
      for (int q = 0; q < 4; ++q) {
        float rk = rowp[k0w + q];
        float kk2 = rowp[64 + k0w + q];
        float wk = rowp[128 + k0w + q];
        float a = kk2 * vv;
        acc = fmaf(rk, fmaf(u_[q], a, s_[q]), acc);
        s_[q] = fmaf(wk, s_[q], a);
      }
      acc += __shfl_xor(acc, 32);   // fold the two k-sub-slots (same d)
      if (lane < 32) pt[t][wv][d32] = acc;
    }
  };
  auto reduce = [&](int g, float (*pt)[8][34]) {
    int tt = tid >> 5, dd = tid & 31;
    float tot = pt[tt][0][dd] + pt[tt][1][dd] + pt[tt][2][dd] + pt[tt][3][dd] +
                pt[tt][4][dd] + pt[tt][5][dd] + pt[tt][6][dd] + pt[tt][7][dd];
    att[base + (size_t)(g * GS + tt) * EE + dh * 32 + dd] = tot;
  };

  // prologue: group 0 -> LDS buf0; group 1 -> rA (in flight)
  *(float4*)&bufAll[0][loff0] = *(const float4*)lsrc0;
  if (has1) *(float4*)&bufAll[0][loff1] = *(const float4*)lsrc1;
  float4 ra0, ra1, rb0, rb1;
  ra0 = *(const float4*)(lsrc0 + (size_t)GS * EE);
  if (has1) ra1 = *(const float4*)(lsrc1 + (size_t)GS * EE);
  barrier_lgkm_only();
  for (int gg = 0; gg < 32; gg += 2) {
    // even group g = gg: uses buf0, part[0]
    if (gg + 2 < 32) {
      rb0 = *(const float4*)(lsrc0 + (size_t)(gg + 2) * GS * EE);
      if (has1) rb1 = *(const float4*)(lsrc1 + (size_t)(gg + 2) * GS * EE);
    }
    compute(bufAll[0], part[0]);
    *(float4*)&bufAll[1][loff0] = ra0;     // group gg+1 (always valid)
    if (has1) *(float4*)&bufAll[1][loff1] = ra1;
    barrier_lgkm_only();
    reduce(gg, part[0]);
    // odd group g = gg+1: uses buf1, part[1]
    if (gg + 3 < 32) {
      ra0 = *(const float4*)(lsrc0 + (size_t)(gg + 3) * GS * EE);
      if (has1) ra1 = *(const float4*)(lsrc1 + (size_t)(gg + 3) * GS * EE);
    }
    compute(bufAll[1], part[1]);
    if (gg + 2 < 32) {
      *(float4*)&bufAll[0][loff0] = rb0;   // group gg+2
      if (has1) *(float4*)&bufAll[0][loff1] = rb1;
    }
    barrier_lgkm_only();
    reduce(gg + 1, part[1]);
  }
}

// ---------------- GroupNorm (per head) + gate, out bf16 ----------------
__global__ void __launch_bounds__(256) gn_gate_kernel(const float* __restrict__ att,
                                                      const float* __restrict__ g,
                                                      const float* __restrict__ gnw,
                                                      const float* __restrict__ gnb,
                                                      unsigned short* __restrict__ attg) {
  int tok = blockIdx.x, tid = threadIdx.x;
  int h = tid >> 3, j = tid & 7;
  size_t base = (size_t)tok * EE + h * 64 + j * 8;
  int e = h * 64 + j * 8;
  float4 a0 = *(const float4*)&att[base];
  float4 a1 = *(const float4*)&att[base + 4];
  float s = a0.x + a0.y + a0.z + a0.w + a1.x + a1.y + a1.z + a1.w;
  s += __shfl_xor(s, 1); s += __shfl_xor(s, 2); s += __shfl_xor(s, 4);
  float mean = s * (1.f / 64.f);
  float d, q = 0.f;
  d = a0.x - mean; q += d * d; d = a0.y - mean; q += d * d;
  d = a0.z - mean; q += d * d; d = a0.w - mean; q += d * d;
  d = a1.x - mean; q += d * d; d = a1.y - mean; q += d * d;
  d = a1.z - mean; q += d * d; d = a1.w - mean; q += d * d;
  q += __shfl_xor(q, 1); q += __shfl_xor(q, 2); q += __shfl_xor(q, 4);
  float rstd = rsqrtf(q * (1.f / 64.f) + EPSF);
  float4 w0 = *(const float4*)&gnw[e], w1 = *(const float4*)&gnw[e + 4];
  float4 b0 = *(const float4*)&gnb[e], b1 = *(const float4*)&gnb[e + 4];
  float4 g0 = *(const float4*)&g[base], g1 = *(const float4*)&g[base + 4];
  ushort4 o0, o1;
  o0.x = f2bf(((a0.x - mean) * rstd * w0.x + b0.x) * g0.x);
  o0.y = f2bf(((a0.y - mean) * rstd * w0.y + b0.y) * g0.y);
  o0.z = f2bf(((a0.z - mean) * rstd * w0.z + b0.z) * g0.z);
  o0.w = f2bf(((a0.w - mean) * rstd * w0.w + b0.w) * g0.w);
  o1.x = f2bf(((a1.x - mean) * rstd * w1.x + b1.x) * g1.x);
  o1.y = f2bf(((a1.y - mean) * rstd * w1.y + b1.y) * g1.y);
  o1.z = f2bf(((a1.z - mean) * rstd * w1.z + b1.z) * g1.z);
  o1.w = f2bf(((a1.w - mean) * rstd * w1.w + b1.w) * g1.w);
  *(ushort4*)&attg[base] = o0;
  *(ushort4*)&attg[base + 4] = o1;
}

extern "C" void kernel_launch(void* const* d_in, const int* in_sizes, int n_in,
                              void* d_out, int out_size, void* d_ws, size_t ws_size,
                              hipStream_t stream) {
  const float* x = (const float*)d_in[0];
  const float* state = (const float*)d_in[1];
  const float* ln1_w = (const float*)d_in[2];
  const float* ln1_b = (const float*)d_in[3];
  const float* ln2_w = (const float*)d_in[4];
  const float* ln2_b = (const float*)d_in[5];
  const float* maa_x = (const float*)d_in[6];
  const float* maa_w1 = (const float*)d_in[7];
  const float* maa_w2 = (const float*)d_in[8];
  const float* maa_stack = (const float*)d_in[9];
  const float* time_decay = (const float*)d_in[10];
  const float* decay_w1 = (const float*)d_in[11];
  const float* decay_w2 = (const float*)d_in[12];
  const float* faaaa = (const float*)d_in[13];
  const float* Wr = (const float*)d_in[14];
  const float* Wk = (const float*)d_in[15];
  const float* Wv = (const float*)d_in[16];
  const float* Wg = (const float*)d_in[17];
  const float* Wo = (const float*)d_in[18];
  const float* gn_w = (const float*)d_in[19];
  const float* gn_b = (const float*)d_in[20];
  const float* ffn_maa_k = (const float*)d_in[21];
  const float* ffn_maa_r = (const float*)d_in[22];
  const float* fWk = (const float*)d_in[23];
  const float* fWr = (const float*)d_in[24];
  const float* fWv = (const float*)d_in[25];
  const int* ip = (const int*)d_in[26];

  char* ws = (char*)d_ws;
  const size_t MB1 = 1024 * 1024;
  unsigned short* WB0 = (unsigned short*)ws;                       // 8 MB
  unsigned short* WB1 = (unsigned short*)(ws + 8 * MB1);           // 8 MB
  float* xn = (float*)(ws + 16 * MB1);                             // 16 MB (also WB2/WB3, att)
  unsigned short* x5b = (unsigned short*)(ws + 32 * MB1);          // 5 x 8 MB
  float* wbuf = (float*)(ws + 72 * MB1);                           // 16 MB (xxm in low 8)
  float* rbuf = (float*)(ws + 88 * MB1);                           // 16 MB
  float* kbuf = (float*)(ws + 104 * MB1);                          // 16 MB
  float* vbuf = (float*)(ws + 120 * MB1);                          // 16 MB
  float* gbuf = (float*)(ws + 136 * MB1);                          // 16 MB (sx first)
  char* smalls = ws + 152 * MB1;                                   // ~6.8 MB
  unsigned short* th = (unsigned short*)smalls;                    // 1 MB
  unsigned short* w1T = (unsigned short*)(smalls + 1 * MB1);       // 1 MB
  unsigned short* w2cat = (unsigned short*)(smalls + 2 * MB1);     // 3.28 MB
  unsigned short* dw1T = (unsigned short*)(smalls + 5376 * 1024);  // 0.5 MB
  unsigned short* dw2T = (unsigned short*)(smalls + 5888 * 1024);  // 0.5 MB
  unsigned short* dt = (unsigned short*)(smalls + 6400 * 1024);    // 0.5 MB

  unsigned short* xxm = (unsigned short*)wbuf;
  float* sx = gbuf;
  float* att = xn;
  unsigned short* WB2 = (unsigned short*)xn;  // xn dead after x5 assemble
  unsigned short* WB3 = WB2 + NEL;
  unsigned short* attg = x5b;               // slot0 (dead after Wo GEMM)
  unsigned short* xkb = x5b;                // slot0 (written after Wo GEMM consumed attg)
  unsigned short* fWvB = x5b + 1 * NEL;     // slot1 (x5_1 dead after dt GEMM)
  unsigned short* xrb = x5b + 2 * NEL;      // slot2
  unsigned short* kkb = x5b + 3 * NEL;      // slot3
  unsigned short* fWkB = x5b + 4 * NEL;     // slot4 (dead after proj4)
  float* rrraw = wbuf;

  const int thr = 256;
  const int nconv = (int)(NEL / 4);

  // 1. fused LN1 + token shift -> xn, xxm, sx
  ln_shift_kernel<0><<<BBATCH * LL, thr, 0, stream>>>(x, state, ip, ln1_w, ln1_b, maa_x,
                                                      nullptr, xn, xxm, sx, nullptr);
  // 2. merged weight preps
  wprep_kernel<<<10496, thr, 0, stream>>>(maa_w1, maa_w2, decay_w1, decay_w2, w1T, w2cat,
                                          dw1T, dw2T);
  // 3. th = tanh(xxm @ w1T)
  gemm_bt<5, 64, 64, 64><<<128, thr, 0, stream>>>(xxm, 2048, w1T, 2048, 2048, 4, th, 256,
                                                  nullptr, nullptr, nullptr);
  // 4. x5 assemble: N=10240, K=160 (BK=32, T=5)
  gemm_bt<7, 128, 128, 32><<<1280, thr, 0, stream>>>(th, 256, w2cat, 160, 160, 80, x5b, 0,
                                                     xn, sx, maa_stack);
  // 5. dt = tanh(x5_1 @ dw1T)
  gemm_bt<5, 64, 64, 64><<<64, thr, 0, stream>>>(x5b + 1 * NEL, 2048, dw1T, 2048, 2048, 2,
                                                 dt, 128, nullptr, nullptr, nullptr);
  // 6. w = exp(-exp(td + dt @ dw2T)): K=128 (T=2)
  gemm_bt<6, 128, 128, 64><<<256, thr, 0, stream>>>(dt, 128, dw2T, 128, 128, 16, wbuf, 2048,
                                                    time_decay, nullptr, nullptr);
  // 7. batched conversion A: Wk,Wv,Wr,Wg
  {
    CvArgs ca;
    ca.s[0] = Wk; ca.d[0] = WB0;
    ca.s[1] = Wv; ca.d[1] = WB1;
    ca.s[2] = Wr; ca.d[2] = WB2;
    ca.s[3] = Wg; ca.d[3] = WB3;
    f2bf_batch<<<dim3(4096, 4), thr, 0, stream>>>(ca, nconv);
  }
  // 8. batched k,v,r,g projections: 256^2 tiles, grid 256 x 512 thr, 2-XCD pinning, SPLIT
  {
    Proj4Args pa;
    pa.A[0] = x5b + 0 * NEL; pa.W[0] = WB0; pa.C[0] = kbuf;
    pa.A[1] = x5b + 2 * NEL; pa.W[1] = WB1; pa.C[1] = vbuf;
    pa.A[2] = x5b + 3 * NEL; pa.W[2] = WB2; pa.C[2] = rbuf;
    pa.A[3] = x5b + 4 * NEL; pa.W[3] = WB3; pa.C[3] = gbuf;
    gemm_proj4<<<256, 512, 0, stream>>>(pa);
  }
  // 9. batched conversion B: Wo->WB0, fWr->WB1, fWk->slot4, fWv->slot1
  {
    CvArgs cb;
    cb.s[0] = Wo; cb.d[0] = WB0;
    cb.s[1] = fWr; cb.d[1] = WB1;
    cb.s[2] = fWk; cb.d[2] = fWkB;
    cb.s[3] = fWv; cb.d[3] = fWvB;
    f2bf_batch<<<dim3(4096, 4), thr, 0, stream>>>(cb, nconv);
  }
  // 10. scan v8 (d-split; disjoint stores; 2-deep prefetch; 1 barrier/group)
  scan_kernel<<<256, 512, 0, stream>>>(rbuf, kbuf, vbuf, wbuf, state, faaaa, ip, att);
  // 11. groupnorm + gate
  gn_gate_kernel<<<BBATCH * LL, thr, 0, stream>>>(att, gbuf, gn_w, gn_b, attg);
  // 12. out = x + attg @ Wo^T
  gemm_bt<2, 128, 64, 64><<<512, thr, 0, stream>>>(attg, 2048, WB0, 2048, 2048, 32,
                                                   (float*)d_out, 2048, x, nullptr, nullptr);
  // 13. fused LN2 + FFN shift (reads d_out, writes xkb(slot0)/xrb(slot2))
  ln_shift_kernel<1><<<BBATCH * LL, thr, 0, stream>>>((const float*)d_out, state, ip, ln2_w,
                                                      ln2_b, ffn_maa_k, ffn_maa_r, nullptr,
                                                      xkb, nullptr, xrb);
  // 14. batched rr + kk: grid 512, per-GEMM 4-XCD pinning
  gemm_ffn2<<<512, thr, 0, stream>>>(xrb, xkb, WB1, fWkB, rrraw, kkb);
  // 15. out += sigmoid(rr) * (kk @ fWv^T)
  gemm_bt<3, 128, 64, 64><<<512, thr, 0, stream>>>(kkb, 2048, fWvB, 2048, 2048, 32,
                                                   (float*)d_out, 2048, (const float*)d_out,
                                                   rrraw, nullptr);
}

// Round 18
// 397.072 us; speedup vs baseline: 1.0990x; 1.0325x over previous
//
#include <hip/hip_runtime.h>

#define EE 2048
#define LL 512
#define BBATCH 4
#define HH 32
#define SS 64
#define EPSF 1e-5f
static constexpr size_t NEL = (size_t)BBATCH * LL * EE;  // 4,194,304

typedef __attribute__((ext_vector_type(8))) short short8;
typedef __attribute__((ext_vector_type(4))) float f32x4;

__device__ __forceinline__ unsigned short f2bf(float f) {
  union { float f; unsigned u; } x; x.f = f;
  return (unsigned short)((x.u + 0x7fffu + ((x.u >> 16) & 1u)) >> 16);
}

__device__ __forceinline__ void gload_lds16(const unsigned short* g, unsigned short* l) {
  __builtin_amdgcn_global_load_lds((const __attribute__((address_space(1))) void*)g,
                                   (__attribute__((address_space(3))) void*)l, 16, 0, 0);
}

template <int N>
__device__ __forceinline__ void wait_vmcnt_n() {
  if constexpr (N == 4) asm volatile("s_waitcnt vmcnt(4)" ::: "memory");
  else if constexpr (N == 6) asm volatile("s_waitcnt vmcnt(6)" ::: "memory");
  else if constexpr (N == 8) asm volatile("s_waitcnt vmcnt(8)" ::: "memory");
  else asm volatile("s_waitcnt vmcnt(0)" ::: "memory");
}

__device__ __forceinline__ void barrier_lgkm_only() {
  asm volatile("s_waitcnt lgkmcnt(0)" ::: "memory");
  __builtin_amdgcn_sched_barrier(0);
  __builtin_amdgcn_s_barrier();
}

struct CvArgs {
  const float* s[4];
  unsigned short* d[4];
};

// ---------------- merged weight prep: w1T, w2cat, dw1T, dw2T ----------------
__global__ void __launch_bounds__(256) wprep_kernel(const float* __restrict__ w1,
                                                    const float* __restrict__ w2,
                                                    const float* __restrict__ d1,
                                                    const float* __restrict__ d2,
                                                    unsigned short* __restrict__ w1T,
                                                    unsigned short* __restrict__ w2cat,
                                                    unsigned short* __restrict__ dw1T,
                                                    unsigned short* __restrict__ dw2T) {
  const int N0 = 256 * 2048;
  const int N1 = 10240 * 160;
  const int N2 = 128 * 2048;
  const int N3 = 2048 * 128;
  int id = blockIdx.x * 256 + threadIdx.x;
  if (id < N0) {
    int n = id >> 11, k = id & 2047;
    float v = (n < 160) ? w1[(size_t)k * 160 + n] : 0.f;
    w1T[id] = f2bf(v);
    return;
  }
  id -= N0;
  if (id < N1) {
    int n = id / 160, kq = id - n * 160;
    int j = n >> 11, e = n & 2047;
    float v = ((kq >> 5) == j) ? w2[(size_t)kq * 2048 + e] : 0.f;
    w2cat[id] = f2bf(v);
    return;
  }
  id -= N1;
  if (id < N2) {
    int n = id >> 11, k = id & 2047;
    float v = (n < 64) ? d1[(size_t)k * 64 + n] : 0.f;
    dw1T[id] = f2bf(v);
    return;
  }
  id -= N2;
  if (id < N3) {
    int n = id >> 7, k = id & 127;
    float v = (k < 64) ? d2[(size_t)k * 2048 + n] : 0.f;
    dw2T[id] = f2bf(v);
  }
}

// ---------------- fused LN + token-shift ----------------
template <int SIDE>
__global__ void __launch_bounds__(256) ln_shift_kernel(
    const float* __restrict__ x, const float* __restrict__ state, const int* __restrict__ ip,
    const float* __restrict__ lnw, const float* __restrict__ lnb,
    const float* __restrict__ mA, const float* __restrict__ mB,
    float* __restrict__ xn_out, unsigned short* __restrict__ o1,
    float* __restrict__ sx_out, unsigned short* __restrict__ o2) {
  __shared__ float red[8];
  int tok = blockIdx.x;
  int b = tok >> 9, t = tok & 511;
  int tid = threadIdx.x;
  int e = tid * 8;
  size_t base = (size_t)tok * EE;
  float c[8], p[8];
  *(float4*)&c[0] = *(const float4*)&x[base + e];
  *(float4*)&c[4] = *(const float4*)&x[base + e + 4];
  bool hasp = (t != 0);
  if (hasp) {
    *(float4*)&p[0] = *(const float4*)&x[base - EE + e];
    *(float4*)&p[4] = *(const float4*)&x[base - EE + e + 4];
  } else {
    const float* srow = state + ((size_t)b * (2 + SS) + (size_t)(2 + SS) * (*ip) +
                                 (SIDE == 0 ? 1 : 0)) * EE;
    *(float4*)&p[0] = *(const float4*)&srow[e];
    *(float4*)&p[4] = *(const float4*)&srow[e + 4];
  }
  float sc = 0.f, sp = 0.f;
#pragma unroll
  for (int j = 0; j < 8; ++j) { sc += c[j]; sp += p[j]; }
#pragma unroll
  for (int off = 32; off >= 1; off >>= 1) {
    sc += __shfl_xor(sc, off);
    sp += __shfl_xor(sp, off);
  }
  if ((tid & 63) == 0) { red[tid >> 6] = sc; red[4 + (tid >> 6)] = sp; }
  __syncthreads();
  float mc = (red[0] + red[1] + red[2] + red[3]) * (1.f / EE);
  float mp = (red[4] + red[5] + red[6] + red[7]) * (1.f / EE);
  __syncthreads();
  float qc = 0.f, qp = 0.f;
#pragma unroll
  for (int j = 0; j < 8; ++j) {
    float dc = c[j] - mc, dp = p[j] - mp;
    qc += dc * dc; qp += dp * dp;
  }
#pragma unroll
  for (int off = 32; off >= 1; off >>= 1) {
    qc += __shfl_xor(qc, off);
    qp += __shfl_xor(qp, off);
  }
  if ((tid & 63) == 0) { red[tid >> 6] = qc; red[4 + (tid >> 6)] = qp; }
  __syncthreads();
  float rc = rsqrtf((red[0] + red[1] + red[2] + red[3]) * (1.f / EE) + EPSF);
  float rp = rsqrtf((red[4] + red[5] + red[6] + red[7]) * (1.f / EE) + EPSF);
  float wv[8], bv[8], av[8], bv2[8];
  *(float4*)&wv[0] = *(const float4*)&lnw[e];
  *(float4*)&wv[4] = *(const float4*)&lnw[e + 4];
  *(float4*)&bv[0] = *(const float4*)&lnb[e];
  *(float4*)&bv[4] = *(const float4*)&lnb[e + 4];
  *(float4*)&av[0] = *(const float4*)&mA[e];
  *(float4*)&av[4] = *(const float4*)&mA[e + 4];
  if (SIDE == 1) {
    *(float4*)&bv2[0] = *(const float4*)&mB[e];
    *(float4*)&bv2[4] = *(const float4*)&mB[e + 4];
  }
  float cn[8], sxv[8];
#pragma unroll
  for (int j = 0; j < 8; ++j) {
    float cnj = (c[j] - mc) * rc * wv[j] + bv[j];
    float pnj = hasp ? ((p[j] - mp) * rp * wv[j] + bv[j]) : p[j];
    cn[j] = cnj;
    sxv[j] = pnj - cnj;
  }
  if constexpr (SIDE == 0) {
    *(float4*)&xn_out[base + e] = *(float4*)&cn[0];
    *(float4*)&xn_out[base + e + 4] = *(float4*)&cn[4];
    *(float4*)&sx_out[base + e] = *(float4*)&sxv[0];
    *(float4*)&sx_out[base + e + 4] = *(float4*)&sxv[4];
    ushort4 xo0, xo1;
    xo0.x = f2bf(cn[0] + sxv[0] * av[0]); xo0.y = f2bf(cn[1] + sxv[1] * av[1]);
    xo0.z = f2bf(cn[2] + sxv[2] * av[2]); xo0.w = f2bf(cn[3] + sxv[3] * av[3]);
    xo1.x = f2bf(cn[4] + sxv[4] * av[4]); xo1.y = f2bf(cn[5] + sxv[5] * av[5]);
    xo1.z = f2bf(cn[6] + sxv[6] * av[6]); xo1.w = f2bf(cn[7] + sxv[7] * av[7]);
    *(ushort4*)&o1[base + e] = xo0;
    *(ushort4*)&o1[base + e + 4] = xo1;
  } else {
    ushort4 k0, k1, r0, r1;
    k0.x = f2bf(cn[0] + sxv[0] * av[0]); k0.y = f2bf(cn[1] + sxv[1] * av[1]);
    k0.z = f2bf(cn[2] + sxv[2] * av[2]); k0.w = f2bf(cn[3] + sxv[3] * av[3]);
    k1.x = f2bf(cn[4] + sxv[4] * av[4]); k1.y = f2bf(cn[5] + sxv[5] * av[5]);
    k1.z = f2bf(cn[6] + sxv[6] * av[6]); k1.w = f2bf(cn[7] + sxv[7] * av[7]);
    r0.x = f2bf(cn[0] + sxv[0] * bv2[0]); r0.y = f2bf(cn[1] + sxv[1] * bv2[1]);
    r0.z = f2bf(cn[2] + sxv[2] * bv2[2]); r0.w = f2bf(cn[3] + sxv[3] * bv2[3]);
    r1.x = f2bf(cn[4] + sxv[4] * bv2[4]); r1.y = f2bf(cn[5] + sxv[5] * bv2[5]);
    r1.z = f2bf(cn[6] + sxv[6] * bv2[6]); r1.w = f2bf(cn[7] + sxv[7] * bv2[7]);
    *(ushort4*)&o1[base + e] = k0;
    *(ushort4*)&o1[base + e + 4] = k1;
    *(ushort4*)&o2[base + e] = r0;
    *(ushort4*)&o2[base + e + 4] = r1;
  }
}

// ---------------- GEMM: 2-deep counted-vmcnt pipeline ----------------
template <int ROWS, int BK, int NT>
__device__ __forceinline__ void stage_mat(const unsigned short* __restrict__ base, int ld,
                                          int k0, unsigned short* dst) {
  constexpr int GPR = BK / 8;
  constexpr int L = ROWS * GPR / NT;
  int tid = threadIdx.x;
#pragma unroll
  for (int r = 0; r < L; ++r) {
    int g = r * NT + tid;
    int row = g / GPR, p = g & (GPR - 1);
    int lg = p ^ (row & (GPR - 1));  // inverse-swizzled source granule (rule #21)
    gload_lds16(base + (size_t)row * ld + k0 + lg * 8, &dst[g * 8]);
  }
}

// NT threads, WM x WN waves; per-wave tile (BM/WM) x (BN/WN).
template <int BM, int BN, int BK, int NT, int WM, int WN, bool SPLIT = false>
__device__ __forceinline__ void gemm_core(const unsigned short* __restrict__ A, int lda,
                                          const unsigned short* __restrict__ W, int ldw,
                                          int K, int bm, int bn, unsigned short* AsAll,
                                          unsigned short* BsAll,
                                          f32x4 (&acc)[BM / WM / 16][BN / WN / 16],
                                          int& m0o, int& n0o) {
  constexpr int FM = BM / WM / 16, FN = BN / WN / 16, KS = BK / 32;
  constexpr int GPR = BK / 8;
  constexpr int NLD = (BM + BN) * GPR / NT;  // gload_lds per tile per thread
  int tid = threadIdx.x;
  int wave = tid >> 6, lane = tid & 63;
  int wm = wave / WN, wn = wave % WN;
  const unsigned short* Abase = A + (size_t)bm * BM * lda;
  const unsigned short* Bbase = W + (size_t)bn * BN * ldw;
  const int T = K / BK;
  stage_mat<BM, BK, NT>(Abase, lda, 0, AsAll);
  stage_mat<BN, BK, NT>(Bbase, ldw, 0, BsAll);
  {
    int k1 = (T > 1) ? BK : 0;
    stage_mat<BM, BK, NT>(Abase, lda, k1, AsAll + BM * BK);
    stage_mat<BN, BK, NT>(Bbase, ldw, k1, BsAll + BN * BK);
  }
  int q = lane >> 4;
  int rA = wm * (BM / WM) + (lane & 15);
  int rB = wn * (BN / WN) + (lane & 15);
  int xrA = rA & (GPR - 1), xrB = rB & (GPR - 1);
  for (int t = 0; t < T; ++t) {
    unsigned short* As = AsAll + (t & 1) * (BM * BK);
    unsigned short* Bs = BsAll + (t & 1) * (BN * BK);
    wait_vmcnt_n<NLD>();               // tile-t loads landed; tile t+1 stays in flight
    __builtin_amdgcn_s_barrier();
    __builtin_amdgcn_sched_barrier(0);
    short8 av[KS][FM], bv[KS][FN];
#pragma unroll
    for (int ks = 0; ks < KS; ++ks) {
#pragma unroll
      for (int f = 0; f < FM; f++) {
        int p = (ks * 4 + q) ^ xrA;
        av[ks][f] = *(const short8*)&As[(rA + f * 16) * BK + p * 8];
      }
#pragma unroll
      for (int f = 0; f < FN; f++) {
        int p = (ks * 4 + q) ^ xrB;
        bv[ks][f] = *(const short8*)&Bs[(rB + f * 16) * BK + p * 8];
      }
    }
    if constexpr (SPLIT && KS >= 2) {
#pragma unroll
      for (int fm = 0; fm < FM; fm++)
#pragma unroll
        for (int fn = 0; fn < FN; fn++)
          acc[fm][fn] = __builtin_amdgcn_mfma_f32_16x16x32_bf16(av[0][fm], bv[0][fn],
                                                                acc[fm][fn], 0, 0, 0);
    }
    asm volatile("s_waitcnt lgkmcnt(0)" ::: "memory");
    __builtin_amdgcn_sched_barrier(0);
    __builtin_amdgcn_s_barrier();
    int tn = t + 2;
    if (tn >= T) tn -= T;
    stage_mat<BM, BK, NT>(Abase, lda, tn * BK, As);
    stage_mat<BN, BK, NT>(Bbase, ldw, tn * BK, Bs);
    __builtin_amdgcn_s_setprio(1);
    if constexpr (SPLIT && KS >= 2) {
#pragma unroll
      for (int ks = 1; ks < KS; ++ks)
#pragma unroll
        for (int fm = 0; fm < FM; fm++)
#pragma unroll
          for (int fn = 0; fn < FN; fn++)
            acc[fm][fn] = __builtin_amdgcn_mfma_f32_16x16x32_bf16(av[ks][fm], bv[ks][fn],
                                                                  acc[fm][fn], 0, 0, 0);
    } else {
#pragma unroll
      for (int ks = 0; ks < KS; ++ks)
#pragma unroll
        for (int fm = 0; fm < FM; fm++)
#pragma unroll
          for (int fn = 0; fn < FN; fn++)
            acc[fm][fn] = __builtin_amdgcn_mfma_f32_16x16x32_bf16(av[ks][fm], bv[ks][fn],
                                                                  acc[fm][fn], 0, 0, 0);
    }
    __builtin_amdgcn_s_setprio(0);
  }
  m0o = bm * BM + wm * (BM / WM);
  n0o = bn * BN + wn * (BN / WN);
}

template <int FM, int FN, typename F>
__device__ __forceinline__ void epi_loop(f32x4 (&acc)[FM][FN], int m0, int n0, F f) {
  int lane = threadIdx.x & 63;
  int rl = (lane >> 4) * 4, cl = lane & 15;
#pragma unroll
  for (int fm = 0; fm < FM; fm++)
#pragma unroll
    for (int fn = 0; fn < FN; fn++)
#pragma unroll
      for (int q = 0; q < 4; q++)
        f(m0 + fm * 16 + rl + q, n0 + fn * 16 + cl, acc[fm][fn][q]);
}

// MODE 2: f32 p1+acc. 3: f32 p1+sigmoid(p2)*acc. 5: bf16 tanh. 7: x5.
template <int MODE, int BM, int BN, int BK>
__global__ void __launch_bounds__(256) gemm_bt(const unsigned short* __restrict__ A, int lda,
                                               const unsigned short* __restrict__ W, int ldw,
                                               int K, int NB, void* __restrict__ Cout, int ldc,
                                               const float* __restrict__ p1,
                                               const float* __restrict__ p2,
                                               const float* __restrict__ p3) {
  __shared__ __align__(16) unsigned short As[2 * BM * BK];
  __shared__ __align__(16) unsigned short Bs[2 * BN * BK];
  int nwg = gridDim.x, bid = blockIdx.x;
  int qd = nwg >> 3;
  int wg = (bid & 7) * qd + (bid >> 3);  // bijective XCD swizzle (nwg % 8 == 0)
  int bm = wg / NB, bn = wg - bm * NB;
  f32x4 acc[BM / 32][BN / 32] = {};
  int m0, n0;
  gemm_core<BM, BN, BK, 256, 2, 2>(A, lda, W, ldw, K, bm, bn, As, Bs, acc, m0, n0);
  epi_loop(acc, m0, n0, [&](int m, int n, float val) {
    size_t o = (size_t)m * ldc + n;
    if constexpr (MODE == 2) {
      ((float*)Cout)[o] = p1[o] + val;
    } else if constexpr (MODE == 3) {
      ((float*)Cout)[o] = p1[o] + val * (1.f / (1.f + expf(-p2[o])));
    } else if constexpr (MODE == 5) {
      ((unsigned short*)Cout)[o] = f2bf(tanhf(val));
    } else {  // MODE 7: x5 assemble
      int j = n >> 11, e = n & 2047;
      size_t oe = (size_t)m * EE + e;
      float xv = p1[oe];
      float sv = p2[oe];
      float st = p3[(size_t)j * EE + e];
      ((unsigned short*)Cout)[(size_t)j * NEL + oe] = f2bf(xv + sv * (st + val));
    }
  });
}

// ---- fused: w = exp(-exp(td + dt @ dw2T)) GEMM (blocks 0..255) + f2bf-A (blocks 256+) ----
__global__ void __launch_bounds__(256) wgemm_f2bf(const unsigned short* __restrict__ dt,
                                                  const unsigned short* __restrict__ dw2T,
                                                  const float* __restrict__ td,
                                                  float* __restrict__ wout, CvArgs cv) {
  __shared__ __align__(16) unsigned short As[2 * 128 * 64];
  __shared__ __align__(16) unsigned short Bs[2 * 128 * 64];
  if (blockIdx.x >= 256) {
    int fid = blockIdx.x - 256;              // 0..16383
    int z = fid >> 12;                       // block-uniform job id
    size_t i = ((size_t)(fid & 4095)) * 256 + threadIdx.x;  // < 2^20
    float4 v = ((const float4*)cv.s[z])[i];
    ushort4 o;
    o.x = f2bf(v.x); o.y = f2bf(v.y); o.z = f2bf(v.z); o.w = f2bf(v.w);
    ((ushort4*)cv.d[z])[i] = o;
    return;
  }
  int wg = blockIdx.x;
  int bm = wg >> 4, bn = wg & 15;
  f32x4 acc[4][4] = {};
  int m0, n0;
  gemm_core<128, 128, 64, 256, 2, 2>(dt, 128, dw2T, 128, 128, bm, bn, As, Bs, acc, m0, n0);
  epi_loop(acc, m0, n0, [&](int m, int n, float val) {
    wout[(size_t)m * EE + n] = expf(-expf(td[n] + val));
  });
}

// ---- batched 4-GEMM (k,v,r,g projections): 256^2, 8 waves, 2-XCD pinning, SPLIT ----
struct Proj4Args {
  const unsigned short* A[4];
  const unsigned short* W[4];
  float* C[4];
};
__global__ void __launch_bounds__(512, 1) gemm_proj4(Proj4Args args) {
  __shared__ __align__(16) unsigned short As[2 * 256 * 64];  // 64 KB
  __shared__ __align__(16) unsigned short Bs[2 * 256 * 64];  // 64 KB
  int bid = blockIdx.x;
  int xcd = bid & 7;
  int z = xcd >> 1;
  int tile = ((xcd & 1) << 5) + (bid >> 3);
  int bm = tile >> 3, bn = tile & 7;
  f32x4 acc[8][4] = {};
  int m0, n0;
  gemm_core<256, 256, 64, 512, 2, 4, true>(args.A[z], EE, args.W[z], EE, EE, bm, bn, As, Bs,
                                           acc, m0, n0);
  float* C = args.C[z];
  bool silu = (z == 3);
  epi_loop(acc, m0, n0, [&](int m, int n, float val) {
    size_t o = (size_t)m * EE + n;
    C[o] = silu ? (val / (1.f + expf(-val))) : val;
  });
}

// ---- batched 2-GEMM (rr f32 ; kk = relu^2 bf16), 128^2, per-GEMM 4-XCD pinning ----
__global__ void __launch_bounds__(256) gemm_ffn2(const unsigned short* A0,
                                                 const unsigned short* A1,
                                                 const unsigned short* W0,
                                                 const unsigned short* W1, float* C0,
                                                 unsigned short* C1) {
  __shared__ __align__(16) unsigned short As[2 * 128 * 64];
  __shared__ __align__(16) unsigned short Bs[2 * 128 * 64];
  int bid = blockIdx.x;
  int xcd = bid & 7;
  int z = xcd >> 2;
  int tile = ((xcd & 3) << 6) + (bid >> 3);
  int bm = tile >> 4, bn = tile & 15;
  f32x4 acc[4][4] = {};
  int m0, n0;
  gemm_core<128, 128, 64, 256, 2, 2>(z ? A1 : A0, EE, z ? W1 : W0, EE, EE, bm, bn, As, Bs,
                                     acc, m0, n0);
  epi_loop(acc, m0, n0, [&](int m, int n, float val) {
    size_t o = (size_t)m * EE + n;
    if (z == 0) {
      C0[o] = val;
    } else {
      float rv = fmaxf(val, 0.f);
      C1[o] = f2bf(rv * rv);
    }
  });
}

// ---------------- fused WKV scan v8 (blocks 0..255) + f2bf-B (blocks 256+) ----------------
#define GS 16
__global__ void __launch_bounds__(512) scan_f2bf(const float* __restrict__ r,
                                                 const float* __restrict__ k,
                                                 const float* __restrict__ v,
                                                 const float* __restrict__ w,
                                                 const float* __restrict__ state,
                                                 const float* __restrict__ faaaa,
                                                 const int* __restrict__ ip,
                                                 float* __restrict__ att, CvArgs cv) {
  __shared__ float bufAll[2][GS * 224];   // 28 KB
  __shared__ float part[2][GS][8][34];    // 34.8 KB
  if (blockIdx.x >= 256) {
    int fid = blockIdx.x - 256;             // 0..4095
    int z = fid >> 10;                      // block-uniform job id
    size_t base_i = ((size_t)(fid & 1023)) * 512 + threadIdx.x;  // < 2^19
    {
      float4 x0 = ((const float4*)cv.s[z])[base_i];
      ushort4 o;
      o.x = f2bf(x0.x); o.y = f2bf(x0.y); o.z = f2bf(x0.z); o.w = f2bf(x0.w);
      ((ushort4*)cv.d[z])[base_i] = o;
    }
    {
      size_t i2 = base_i + 524288;
      float4 x1 = ((const float4*)cv.s[z])[i2];
      ushort4 o;
      o.x = f2bf(x1.x); o.y = f2bf(x1.y); o.z = f2bf(x1.z); o.w = f2bf(x1.w);
      ((ushort4*)cv.d[z])[i2] = o;
    }
    return;
  }
  int blk = blockIdx.x;
  int bh = blk >> 1, dh = blk & 1;
  int b = bh >> 5, h = bh & 31;
  int tid = threadIdx.x, wv = tid >> 6, lane = tid & 63;
  int d32 = lane & 31;
  int k0w = wv * 8 + (lane >> 5) * 4;
  int dfull = dh * 32 + d32;
  int ii = *ip;
  const float* sb = state + ((size_t)b * (2 + SS) + (size_t)(2 + SS) * ii + 2) * EE;
  float s_[4], u_[4];
#pragma unroll
  for (int q = 0; q < 4; ++q) {
    int kk_ = k0w + q;
    s_[q] = sb[(size_t)(2 * h + (kk_ >> 5)) * EE + (kk_ & 31) * 64 + dfull];
    u_[q] = faaaa[h * 64 + kk_];
  }
  size_t base = (size_t)b * LL * EE + (size_t)h * 64;
  int i0 = tid;
  int row0 = i0 / 56, j0 = i0 - row0 * 56;
  const float* a0p; int off0, gc0;
  if (j0 < 16) { a0p = r; off0 = j0 * 4; gc0 = j0 * 4; }
  else if (j0 < 32) { a0p = k; off0 = 64 + (j0 - 16) * 4; gc0 = (j0 - 16) * 4; }
  else if (j0 < 48) { a0p = w; off0 = 128 + (j0 - 32) * 4; gc0 = (j0 - 32) * 4; }
  else { a0p = v; off0 = 192 + (j0 - 48) * 4; gc0 = dh * 32 + (j0 - 48) * 4; }
  const float* lsrc0 = a0p + base + (size_t)row0 * EE + gc0;
  int loff0 = row0 * 224 + off0;
  bool has1 = (tid < 384);
  int i1 = tid + 512;
  int row1 = i1 / 56, j1 = i1 - row1 * 56;
  const float* a1p; int off1, gc1;
  if (j1 < 16) { a1p = r; off1 = j1 * 4; gc1 = j1 * 4; }
  else if (j1 < 32) { a1p = k; off1 = 64 + (j1 - 16) * 4; gc1 = (j1 - 16) * 4; }
  else if (j1 < 48) { a1p = w; off1 = 128 + (j1 - 32) * 4; gc1 = (j1 - 32) * 4; }
  else { a1p = v; off1 = 192 + (j1 - 48) * 4; gc1 = dh * 32 + (j1 - 48) * 4; }
  const float* lsrc1 = a1p + base + (size_t)row1 * EE + gc1;
  int loff1 = row1 * 224 + off1;

  auto compute = [&](const float* buf, float (*pt)[8][34]) {
#pragma unroll
    for (int t = 0; t < GS; ++t) {
      const float* rowp = buf + t * 224;
      float vv = rowp[192 + d32];
      float acc = 0.f;
#pragma unroll
      for (int q = 0; q < 4; ++q) {
        float rk = rowp[k0w + q];
        float kk2 = rowp[64 + k0w + q];
        float wk = rowp[128 + k0w + q];
        float a = kk2 * vv;
        acc = fmaf(rk, fmaf(u_[q], a, s_[q]), acc);
        s_[q] = fmaf(wk, s_[q], a);
      }
      acc += __shfl_xor(acc, 32);
      if (lane < 32) pt[t][wv][d32] = acc;
    }
  };
  auto reduce = [&](int g, float (*pt)[8][34]) {
    int tt = tid >> 5, dd = tid & 31;
    float tot = pt[tt][0][dd] + pt[tt][1][dd] + pt[tt][2][dd] + pt[tt][3][dd] +
                pt[tt][4][dd] + pt[tt][5][dd] + pt[tt][6][dd] + pt[tt][7][dd];
    att[base + (size_t)(g * GS + tt) * EE + dh * 32 + dd] = tot;
  };

  *(float4*)&bufAll[0][loff0] = *(const float4*)lsrc0;
  if (has1) *(float4*)&bufAll[0][loff1] = *(const float4*)lsrc1;
  float4 ra0, ra1, rb0, rb1;
  ra0 = *(const float4*)(lsrc0 + (size_t)GS * EE);
  if (has1) ra1 = *(const float4*)(lsrc1 + (size_t)GS * EE);
  barrier_lgkm_only();
  for (int gg = 0; gg < 32; gg += 2) {
    if (gg + 2 < 32) {
      rb0 = *(const float4*)(lsrc0 + (size_t)(gg + 2) * GS * EE);
      if (has1) rb1 = *(const float4*)(lsrc1 + (size_t)(gg + 2) * GS * EE);
    }
    compute(bufAll[0], part[0]);
    *(float4*)&bufAll[1][loff0] = ra0;
    if (has1) *(float4*)&bufAll[1][loff1] = ra1;
    barrier_lgkm_only();
    reduce(gg, part[0]);
    if (gg + 3 < 32) {
      ra0 = *(const float4*)(lsrc0 + (size_t)(gg + 3) * GS * EE);
      if (has1) ra1 = *(const float4*)(lsrc1 + (size_t)(gg + 3) * GS * EE);
    }
    compute(bufAll[1], part[1]);
    if (gg + 2 < 32) {
      *(float4*)&bufAll[0][loff0] = rb0;
      if (has1) *(float4*)&bufAll[0][loff1] = rb1;
    }
    barrier_lgkm_only();
    reduce(gg + 1, part[1]);
  }
}

// ---------------- GroupNorm (per head) + gate, out bf16 ----------------
__global__ void __launch_bounds__(256) gn_gate_kernel(const float* __restrict__ att,
                                                      const float* __restrict__ g,
                                                      const float* __restrict__ gnw,
                                                      const float* __restrict__ gnb,
                                                      unsigned short* __restrict__ attg) {
  int tok = blockIdx.x, tid = threadIdx.x;
  int h = tid >> 3, j = tid & 7;
  size_t base = (size_t)tok * EE + h * 64 + j * 8;
  int e = h * 64 + j * 8;
  float4 a0 = *(const float4*)&att[base];
  float4 a1 = *(const float4*)&att[base + 4];
  float s = a0.x + a0.y + a0.z + a0.w + a1.x + a1.y + a1.z + a1.w;
  s += __shfl_xor(s, 1); s += __shfl_xor(s, 2); s += __shfl_xor(s, 4);
  float mean = s * (1.f / 64.f);
  float d, q = 0.f;
  d = a0.x - mean; q += d * d; d = a0.y - mean; q += d * d;
  d = a0.z - mean; q += d * d; d = a0.w - mean; q += d * d;
  d = a1.x - mean; q += d * d; d = a1.y - mean; q += d * d;
  d = a1.z - mean; q += d * d; d = a1.w - mean; q += d * d;
  q += __shfl_xor(q, 1); q += __shfl_xor(q, 2); q += __shfl_xor(q, 4);
  float rstd = rsqrtf(q * (1.f / 64.f) + EPSF);
  float4 w0 = *(const float4*)&gnw[e], w1 = *(const float4*)&gnw[e + 4];
  float4 b0 = *(const float4*)&gnb[e], b1 = *(const float4*)&gnb[e + 4];
  float4 g0 = *(const float4*)&g[base], g1 = *(const float4*)&g[base + 4];
  ushort4 o0, o1;
  o0.x = f2bf(((a0.x - mean) * rstd * w0.x + b0.x) * g0.x);
  o0.y = f2bf(((a0.y - mean) * rstd * w0.y + b0.y) * g0.y);
  o0.z = f2bf(((a0.z - mean) * rstd * w0.z + b0.z) * g0.z);
  o0.w = f2bf(((a0.w - mean) * rstd * w0.w + b0.w) * g0.w);
  o1.x = f2bf(((a1.x - mean) * rstd * w1.x + b1.x) * g1.x);
  o1.y = f2bf(((a1.y - mean) * rstd * w1.y + b1.y) * g1.y);
  o1.z = f2bf(((a1.z - mean) * rstd * w1.z + b1.z) * g1.z);
  o1.w = f2bf(((a1.w - mean) * rstd * w1.w + b1.w) * g1.w);
  *(ushort4*)&attg[base] = o0;
  *(ushort4*)&attg[base + 4] = o1;
}

extern "C" void kernel_launch(void* const* d_in, const int* in_sizes, int n_in,
                              void* d_out, int out_size, void* d_ws, size_t ws_size,
                              hipStream_t stream) {
  const float* x = (const float*)d_in[0];
  const float* state = (const float*)d_in[1];
  const float* ln1_w = (const float*)d_in[2];
  const float* ln1_b = (const float*)d_in[3];
  const float* ln2_w = (const float*)d_in[4];
  const float* ln2_b = (const float*)d_in[5];
  const float* maa_x = (const float*)d_in[6];
  const float* maa_w1 = (const float*)d_in[7];
  const float* maa_w2 = (const float*)d_in[8];
  const float* maa_stack = (const float*)d_in[9];
  const float* time_decay = (const float*)d_in[10];
  const float* decay_w1 = (const float*)d_in[11];
  const float* decay_w2 = (const float*)d_in[12];
  const float* faaaa = (const float*)d_in[13];
  const float* Wr = (const float*)d_in[14];
  const float* Wk = (const float*)d_in[15];
  const float* Wv = (const float*)d_in[16];
  const float* Wg = (const float*)d_in[17];
  const float* Wo = (const float*)d_in[18];
  const float* gn_w = (const float*)d_in[19];
  const float* gn_b = (const float*)d_in[20];
  const float* ffn_maa_k = (const float*)d_in[21];
  const float* ffn_maa_r = (const float*)d_in[22];
  const float* fWk = (const float*)d_in[23];
  const float* fWr = (const float*)d_in[24];
  const float* fWv = (const float*)d_in[25];
  const int* ip = (const int*)d_in[26];

  char* ws = (char*)d_ws;
  const size_t MB1 = 1024 * 1024;
  unsigned short* WB0 = (unsigned short*)ws;                       // 8 MB
  unsigned short* WB1 = (unsigned short*)(ws + 8 * MB1);           // 8 MB
  float* xn = (float*)(ws + 16 * MB1);                             // 16 MB (also WB2/WB3, att)
  unsigned short* x5b = (unsigned short*)(ws + 32 * MB1);          // 5 x 8 MB
  float* wbuf = (float*)(ws + 72 * MB1);                           // 16 MB (xxm in low 8)
  float* rbuf = (float*)(ws + 88 * MB1);                           // 16 MB
  float* kbuf = (float*)(ws + 104 * MB1);                          // 16 MB
  float* vbuf = (float*)(ws + 120 * MB1);                          // 16 MB
  float* gbuf = (float*)(ws + 136 * MB1);                          // 16 MB (sx first)
  char* smalls = ws + 152 * MB1;                                   // ~6.8 MB
  unsigned short* th = (unsigned short*)smalls;                    // 1 MB
  unsigned short* w1T = (unsigned short*)(smalls + 1 * MB1);       // 1 MB
  unsigned short* w2cat = (unsigned short*)(smalls + 2 * MB1);     // 3.28 MB
  unsigned short* dw1T = (unsigned short*)(smalls + 5376 * 1024);  // 0.5 MB
  unsigned short* dw2T = (unsigned short*)(smalls + 5888 * 1024);  // 0.5 MB
  unsigned short* dt = (unsigned short*)(smalls + 6400 * 1024);    // 0.5 MB

  unsigned short* xxm = (unsigned short*)wbuf;
  float* sx = gbuf;
  float* att = xn;
  unsigned short* WB2 = (unsigned short*)xn;  // xn dead after x5 assemble
  unsigned short* WB3 = WB2 + NEL;
  unsigned short* attg = x5b;               // slot0 (dead after Wo GEMM)
  unsigned short* xkb = x5b;                // slot0 (after Wo GEMM consumed attg)
  unsigned short* fWvB = x5b + 1 * NEL;     // slot1 (x5_1 dead after dt GEMM)
  unsigned short* xrb = x5b + 2 * NEL;      // slot2
  unsigned short* kkb = x5b + 3 * NEL;      // slot3
  unsigned short* fWkB = x5b + 4 * NEL;     // slot4 (dead after proj4)
  float* rrraw = wbuf;

  const int thr = 256;

  // 1. fused LN1 + token shift -> xn, xxm, sx
  ln_shift_kernel<0><<<BBATCH * LL, thr, 0, stream>>>(x, state, ip, ln1_w, ln1_b, maa_x,
                                                      nullptr, xn, xxm, sx, nullptr);
  // 2. merged weight preps
  wprep_kernel<<<10496, thr, 0, stream>>>(maa_w1, maa_w2, decay_w1, decay_w2, w1T, w2cat,
                                          dw1T, dw2T);
  // 3. th = tanh(xxm @ w1T)
  gemm_bt<5, 64, 64, 64><<<128, thr, 0, stream>>>(xxm, 2048, w1T, 2048, 2048, 4, th, 256,
                                                  nullptr, nullptr, nullptr);
  // 4. x5 assemble: N=10240, K=160 (BK=32, T=5)
  gemm_bt<7, 128, 128, 32><<<1280, thr, 0, stream>>>(th, 256, w2cat, 160, 160, 80, x5b, 0,
                                                     xn, sx, maa_stack);
  // 5. dt = tanh(x5_1 @ dw1T)
  gemm_bt<5, 64, 64, 64><<<64, thr, 0, stream>>>(x5b + 1 * NEL, 2048, dw1T, 2048, 2048, 2,
                                                 dt, 128, nullptr, nullptr, nullptr);
  // 6. fused: w-GEMM + f2bf-A (Wk->WB0, Wv->WB1, Wr->WB2, Wg->WB3; xn dead now)
  {
    CvArgs ca;
    ca.s[0] = Wk; ca.d[0] = WB0;
    ca.s[1] = Wv; ca.d[1] = WB1;
    ca.s[2] = Wr; ca.d[2] = WB2;
    ca.s[3] = Wg; ca.d[3] = WB3;
    wgemm_f2bf<<<256 + 16384, thr, 0, stream>>>(dt, dw2T, time_decay, wbuf, ca);
  }
  // 7. batched k,v,r,g projections: 256^2 tiles, grid 256 x 512 thr, 2-XCD pinning, SPLIT
  {
    Proj4Args pa;
    pa.A[0] = x5b + 0 * NEL; pa.W[0] = WB0; pa.C[0] = kbuf;
    pa.A[1] = x5b + 2 * NEL; pa.W[1] = WB1; pa.C[1] = vbuf;
    pa.A[2] = x5b + 3 * NEL; pa.W[2] = WB2; pa.C[2] = rbuf;
    pa.A[3] = x5b + 4 * NEL; pa.W[3] = WB3; pa.C[3] = gbuf;
    gemm_proj4<<<256, 512, 0, stream>>>(pa);
  }
  // 8. fused: scan v8 + f2bf-B (Wo->WB0, fWr->WB1, fWk->slot4, fWv->slot1; all dead now)
  {
    CvArgs cb;
    cb.s[0] = Wo; cb.d[0] = WB0;
    cb.s[1] = fWr; cb.d[1] = WB1;
    cb.s[2] = fWk; cb.d[2] = fWkB;
    cb.s[3] = fWv; cb.d[3] = fWvB;
    scan_f2bf<<<256 + 4096, 512, 0, stream>>>(rbuf, kbuf, vbuf, wbuf, state, faaaa, ip,
                                              att, cb);
  }
  // 9. groupnorm + gate
  gn_gate_kernel<<<BBATCH * LL, thr, 0, stream>>>(att, gbuf, gn_w, gn_b, attg);
  // 10. out = x + attg @ Wo^T
  gemm_bt<2, 128, 64, 64><<<512, thr, 0, stream>>>(attg, 2048, WB0, 2048, 2048, 32,
                                                   (float*)d_out, 2048, x, nullptr, nullptr);
  // 11. fused LN2 + FFN shift (reads d_out, writes xkb(slot0)/xrb(slot2))
  ln_shift_kernel<1><<<BBATCH * LL, thr, 0, stream>>>((const float*)d_out, state, ip, ln2_w,
                                                      ln2_b, ffn_maa_k, ffn_maa_r, nullptr,
                                                      xkb, nullptr, xrb);
  // 12. batched rr + kk: grid 512, per-GEMM 4-XCD pinning
  gemm_ffn2<<<512, thr, 0, stream>>>(xrb, xkb, WB1, fWkB, rrraw, kkb);
  // 13. out += sigmoid(rr) * (kk @ fWv^T)
  gemm_bt<3, 128, 64, 64><<<512, thr, 0, stream>>>(kkb, 2048, fWvB, 2048, 2048, 32,
                                                   (float*)d_out, 2048, (const float*)d_out,
                                                   rrraw, nullptr);
}